// Round 11
// baseline (559.415 us; speedup 1.0000x reference)
//
#include <hip/hip_runtime.h>

// ---------------------------------------------------------------------------
// Kernel 0: repack conv2/conv3 weights into chunk-linear [ch][ld*9+tap][oc].
// ---------------------------------------------------------------------------
__global__ __launch_bounds__(256) void repack_kernel(
    const float* __restrict__ cw2, const float* __restrict__ cw3,
    float* __restrict__ packed2, float* __restrict__ packed3)
{
    int t = blockIdx.x * 256 + threadIdx.x;   // grid 72*256 = 18432 = 2*9216
    if (t < 9216) {
        int oc = t & 31, r = t >> 5;          // r = ch*72 + rem in [0,288)
        packed2[t] = cw2[oc * 288 + r];
    } else {
        int t2 = t - 9216;
        int oc = t2 & 31, r = t2 >> 5;
        packed3[t2] = cw3[oc * 288 + r];
    }
}

// ---------------------------------------------------------------------------
// Kernel 1: fused conv stack, one image per 256-thread block (4 waves).
// LDS shrunk to 45.8 KB raw (xs2 row stride 18, plane 292; xs3 overlaid at
// B+3264) so 3 blocks/CU fit after allocation-granule rounding (r10 model:
// 50 KB rounded -> only 2 blocks, 22% occ). Bank math: patch-read row starts
// 18r mod 32 -> at most 2-way wrap overlap (free, m136); weight reads
// broadcast+conflict-free as before.
// ---------------------------------------------------------------------------
__global__ __launch_bounds__(256)
void fused_conv_kernel(
    const float* __restrict__ x,
    const float* __restrict__ cw1, const float* __restrict__ cb1,
    const float* __restrict__ packed2, const float* __restrict__ cb2,
    const float* __restrict__ packed3, const float* __restrict__ cb3,
    float* __restrict__ out3)
{
    const int img = blockIdx.x;
    const int tid = threadIdx.x;

    __shared__ float A[2304];         // xs1/w1s/b1s, later wck
    __shared__ float B[9344];         // xs2 (32 x 292), later scratch + xs3
    __shared__ float b2s[32], b3s[32];

    float* xs1 = A;                   // 900: 30x30 padded image
    float* w1s = A + 900;             // 288: conv1 weights [tap][oc]
    float* b1s = A + 1188;            // 32
    float* wck = A;                   // 2304: weight chunk (after conv1)
    float* xs2 = B;                   // 32 planes x 292 (16 rows x stride 18)
    float* sc  = B;                   // scratch head
    float* xs3 = B + 3264;            // 2880: 32 x 90 (9 rows x stride 10)
                                      // [3264,6144) - created after conv2
                                      // reduction (scratch <=6382) retires,
                                      // disjoint from pool scratch (<=3246)
                                      // and conv3 scratch (<=1222).

    // --- zero xs1 pads + all of xs2 ---
    for (int i = tid; i < 900;  i += 256) xs1[i] = 0.f;
    for (int i = tid; i < 9344; i += 256) B[i] = 0.f;
    __syncthreads();

    // --- stage input image + conv1 weights + biases ---
    for (int i = tid; i < 784; i += 256) {
        int yy = i / 28, xx = i % 28;
        xs1[(yy + 1) * 30 + xx + 1] = x[img * 784 + i];
    }
    for (int i = tid; i < 288; i += 256) {
        int oc = i & 31, tap = i >> 5;
        w1s[i] = cw1[oc * 9 + tap];
    }
    if (tid < 32) { b1s[tid] = cb1[tid]; b2s[tid] = cb2[tid]; b3s[tid] = cb3[tid]; }
    __syncthreads();

    // --- conv1 (1->32) + relu + pool -> xs2 interior rows 1..14, cols 1..14 ---
    {
        const int c1 = tid & 31;
        float w1r[9];
        #pragma unroll
        for (int t = 0; t < 9; t++) w1r[t] = w1s[t * 32 + c1];
        const float bias1 = b1s[c1];
        for (int o = tid; o < 32 * 196; o += 256) {
            int p = o >> 5;
            int py = p / 14, px = p % 14;
            int base = (2 * py) * 30 + 2 * px;
            float P[16];
            #pragma unroll
            for (int r = 0; r < 4; r++) {
                float2 u0 = *(const float2*)&xs1[base + r * 30];
                float2 u1 = *(const float2*)&xs1[base + r * 30 + 2];
                P[r * 4 + 0] = u0.x; P[r * 4 + 1] = u0.y;
                P[r * 4 + 2] = u1.x; P[r * 4 + 3] = u1.y;
            }
            float a00 = 0.f, a01 = 0.f, a10 = 0.f, a11 = 0.f;
            #pragma unroll
            for (int ky = 0; ky < 3; ky++)
                #pragma unroll
                for (int kx = 0; kx < 3; kx++) {
                    float w = w1r[ky * 3 + kx];
                    a00 = fmaf(P[ky * 4 + kx],           w, a00);
                    a01 = fmaf(P[ky * 4 + kx + 1],       w, a01);
                    a10 = fmaf(P[(ky + 1) * 4 + kx],     w, a10);
                    a11 = fmaf(P[(ky + 1) * 4 + kx + 1], w, a11);
                }
            float v = fmaxf(fmaxf(fmaxf(a00, a01), fmaxf(a10, a11)) + bias1, 0.f);
            xs2[c1 * 292 + (py + 1) * 18 + (px + 1)] = v;
        }
    }

    // --- conv2: 4oc x 14 cols, K-split-2 over 4 chunks of 8 ic ---
    const int g  = tid >> 7;            // K-group 0..1 (2 waves each)
    const int u  = tid & 127;           // unit; active if u < 112
    const int cb = u & 7, R = u >> 3;   // oc-quad, prepool row 0..13
    const int oc0 = cb * 4;
    const bool act2 = (u < 112);

    float acc[4][14];
    #pragma unroll
    for (int a = 0; a < 4; a++)
        #pragma unroll
        for (int c = 0; c < 14; c++) acc[a][c] = 0.f;

    float pf[9];                        // next-chunk weight prefetch (2304 = 9*256)
    #pragma unroll
    for (int k = 0; k < 9; k++) pf[k] = packed2[tid + k * 256];

    for (int ch = 0; ch < 4; ch++) {
        __syncthreads();                // conv1/xs2 writes + prior wck reads done
        #pragma unroll
        for (int k = 0; k < 9; k++) wck[tid + k * 256] = pf[k];
        if (ch < 3) {
            #pragma unroll
            for (int k = 0; k < 9; k++) pf[k] = packed2[(ch + 1) * 2304 + tid + k * 256];
        }
        __syncthreads();
        if (act2) {
            #pragma unroll 2
            for (int d = 0; d < 4; d++) {
                const int ld = g * 4 + d;
                const int ic = ch * 8 + ld;
                const float* wd = &wck[ld * 288 + oc0];
                const int pb = ic * 292;
                #pragma unroll
                for (int ky = 0; ky < 3; ky++) {
                    const int rb = pb + (R + ky) * 18;
                    float row[16];
                    #pragma unroll
                    for (int q = 0; q < 4; q++) {
                        const float4 t = *(const float4*)&xs2[rb + q * 4];
                        row[q * 4 + 0] = t.x; row[q * 4 + 1] = t.y;
                        row[q * 4 + 2] = t.z; row[q * 4 + 3] = t.w;
                    }
                    const float4 wa = *(const float4*)&wd[(ky * 3 + 0) * 32];
                    const float4 wb = *(const float4*)&wd[(ky * 3 + 1) * 32];
                    const float4 wc = *(const float4*)&wd[(ky * 3 + 2) * 32];
                    #pragma unroll
                    for (int c = 0; c < 14; c++) {
                        acc[0][c] = fmaf(row[c],     wa.x, acc[0][c]);
                        acc[1][c] = fmaf(row[c],     wa.y, acc[1][c]);
                        acc[2][c] = fmaf(row[c],     wa.z, acc[2][c]);
                        acc[3][c] = fmaf(row[c],     wa.w, acc[3][c]);
                        acc[0][c] = fmaf(row[c + 1], wb.x, acc[0][c]);
                        acc[1][c] = fmaf(row[c + 1], wb.y, acc[1][c]);
                        acc[2][c] = fmaf(row[c + 1], wb.z, acc[2][c]);
                        acc[3][c] = fmaf(row[c + 1], wb.w, acc[3][c]);
                        acc[0][c] = fmaf(row[c + 2], wc.x, acc[0][c]);
                        acc[1][c] = fmaf(row[c + 2], wc.y, acc[1][c]);
                        acc[2][c] = fmaf(row[c + 2], wc.z, acc[2][c]);
                        acc[3][c] = fmaf(row[c + 2], wc.w, acc[3][c]);
                    }
                }
            }
        }
    }

    // --- conv2 K-reduction (1 round, stride-57 scratch; max idx 6382) ---
    __syncthreads();                     // all xs2 patch reads done
    if (g == 1 && act2) {
        #pragma unroll
        for (int a = 0; a < 4; a++)
            #pragma unroll
            for (int c = 0; c < 14; c++) sc[u * 57 + a * 14 + c] = acc[a][c];
    }
    __syncthreads();
    if (g == 0 && act2) {
        #pragma unroll
        for (int a = 0; a < 4; a++)
            #pragma unroll
            for (int c = 0; c < 14; c++) acc[a][c] += sc[u * 57 + a * 14 + c];
    }
    __syncthreads();                     // reduction scratch retires here

    // --- zero xs3 + pool 14x14->7x7 (register hmax + odd/even R exchange) ---
    for (int i = tid; i < 2880; i += 256) xs3[i] = 0.f;
    float hm[4][7];
    if (g == 0 && act2) {
        #pragma unroll
        for (int a = 0; a < 4; a++)
            #pragma unroll
            for (int c = 0; c < 7; c++)
                hm[a][c] = fmaxf(acc[a][2 * c], acc[a][2 * c + 1]);
        if (R & 1) {                     // scratch max idx 111*29+27 = 3246 < 3264
            #pragma unroll
            for (int a = 0; a < 4; a++)
                #pragma unroll
                for (int c = 0; c < 7; c++) sc[u * 29 + a * 7 + c] = hm[a][c];
        }
    }
    __syncthreads();
    if (g == 0 && act2 && !(R & 1)) {
        const int py = R >> 1;           // 0..6
        #pragma unroll
        for (int a = 0; a < 4; a++)
            #pragma unroll
            for (int c = 0; c < 7; c++) {
                float v = fmaxf(hm[a][c], sc[(u + 8) * 29 + a * 7 + c]);
                v = fmaxf(v + b2s[oc0 + a], 0.f);
                xs3[(oc0 + a) * 90 + (py + 1) * 10 + (c + 1)] = v;
            }
    }

    // --- conv3 (32->32, 7x7) + relu + pool(7->3 floor), K-split-2 ---
    const int u3 = tid & 127;
    const bool act3 = (u3 < 72);
    const int cq3 = u3 & 7, pos = u3 >> 3;   // oc-quad, pooled pos 0..8
    const int oc30 = cq3 * 4;
    const int py3 = pos / 3, px3 = pos % 3;
    const int base3 = (2 * py3) * 10 + 2 * px3;

    float a3[4][4];
    #pragma unroll
    for (int a = 0; a < 4; a++)
        #pragma unroll
        for (int q = 0; q < 4; q++) a3[a][q] = 0.f;

    float pg[9];
    #pragma unroll
    for (int k = 0; k < 9; k++) pg[k] = packed3[tid + k * 256];

    for (int ch = 0; ch < 4; ch++) {
        __syncthreads();                 // xs3 writes / prior wck reads done
        #pragma unroll
        for (int k = 0; k < 9; k++) wck[tid + k * 256] = pg[k];
        if (ch < 3) {
            #pragma unroll
            for (int k = 0; k < 9; k++) pg[k] = packed3[(ch + 1) * 2304 + tid + k * 256];
        }
        __syncthreads();
        if (act3) {
            #pragma unroll 2
            for (int d = 0; d < 4; d++) {
                const int ld = g * 4 + d;
                const int ic = ch * 8 + ld;
                const float* xp = &xs3[ic * 90 + base3];
                float P[16];
                #pragma unroll
                for (int r = 0; r < 4; r++) {
                    float2 u0 = *(const float2*)&xp[r * 10];
                    float2 u1 = *(const float2*)&xp[r * 10 + 2];
                    P[r * 4 + 0] = u0.x; P[r * 4 + 1] = u0.y;
                    P[r * 4 + 2] = u1.x; P[r * 4 + 3] = u1.y;
                }
                const float* wd = &wck[ld * 288 + oc30];
                #pragma unroll
                for (int tap = 0; tap < 9; tap++) {
                    const int ky = tap / 3, kx = tap % 3;
                    const float4 wv = *(const float4*)&wd[tap * 32];
                    const float x00 = P[ky * 4 + kx];
                    const float x01 = P[ky * 4 + kx + 1];
                    const float x10 = P[(ky + 1) * 4 + kx];
                    const float x11 = P[(ky + 1) * 4 + kx + 1];
                    a3[0][0] = fmaf(x00, wv.x, a3[0][0]); a3[0][1] = fmaf(x01, wv.x, a3[0][1]);
                    a3[0][2] = fmaf(x10, wv.x, a3[0][2]); a3[0][3] = fmaf(x11, wv.x, a3[0][3]);
                    a3[1][0] = fmaf(x00, wv.y, a3[1][0]); a3[1][1] = fmaf(x01, wv.y, a3[1][1]);
                    a3[1][2] = fmaf(x10, wv.y, a3[1][2]); a3[1][3] = fmaf(x11, wv.y, a3[1][3]);
                    a3[2][0] = fmaf(x00, wv.z, a3[2][0]); a3[2][1] = fmaf(x01, wv.z, a3[2][1]);
                    a3[2][2] = fmaf(x10, wv.z, a3[2][2]); a3[2][3] = fmaf(x11, wv.z, a3[2][3]);
                    a3[3][0] = fmaf(x00, wv.w, a3[3][0]); a3[3][1] = fmaf(x01, wv.w, a3[3][1]);
                    a3[3][2] = fmaf(x10, wv.w, a3[3][2]); a3[3][3] = fmaf(x11, wv.w, a3[3][3]);
                }
            }
        }
    }

    // --- conv3 K-reduction (1 round, stride-17 scratch; max idx 1222) ---
    __syncthreads();
    if (g == 1 && act3) {
        #pragma unroll
        for (int a = 0; a < 4; a++)
            #pragma unroll
            for (int q = 0; q < 4; q++) sc[u3 * 17 + a * 4 + q] = a3[a][q];
    }
    __syncthreads();
    if (g == 0 && act3) {
        #pragma unroll
        for (int a = 0; a < 4; a++)
            #pragma unroll
            for (int q = 0; q < 4; q++) a3[a][q] += sc[u3 * 17 + a * 4 + q];
        float4 res;
        float* r = (float*)&res;
        #pragma unroll
        for (int a = 0; a < 4; a++) {
            float v = fmaxf(fmaxf(a3[a][0], a3[a][1]), fmaxf(a3[a][2], a3[a][3]));
            r[a] = fmaxf(v + b3s[oc30 + a], 0.f);
        }
        *(float4*)&out3[img * 288 + pos * 32 + oc30] = res;
    }
}

// ---------------------------------------------------------------------------
// Kernel 2a/2b: BatchNorm stats, two-stage
// ---------------------------------------------------------------------------
__global__ __launch_bounds__(256) void bn_part_kernel(
    const float* __restrict__ out3, float* __restrict__ pS, float* __restrict__ pSS)
{
    const int blk = blockIdx.x;                   // 64 blocks
    const int c = threadIdx.x & 31, ml = threadIdx.x >> 5;
    float s = 0.f, ss = 0.f;
    const int base = blk * 576 + ml;
    for (int k = 0; k < 72; k++) {
        float v = out3[(base + k * 8) * 32 + c];  // coalesced
        s += v; ss = fmaf(v, v, ss);
    }
    __shared__ float rs[256], rss[256];
    rs[threadIdx.x] = s; rss[threadIdx.x] = ss;
    __syncthreads();
    if (threadIdx.x < 32) {
        float S = 0.f, SS = 0.f;
        #pragma unroll
        for (int m = 0; m < 8; m++) { S += rs[threadIdx.x + 32 * m]; SS += rss[threadIdx.x + 32 * m]; }
        pS[blk * 32 + threadIdx.x] = S;
        pSS[blk * 32 + threadIdx.x] = SS;
    }
}

__global__ __launch_bounds__(64) void bn_final_kernel(
    const float* __restrict__ pS, const float* __restrict__ pSS,
    const float* __restrict__ bng, const float* __restrict__ bnb,
    float* __restrict__ stats)
{
    int c = threadIdx.x;
    if (c < 32) {
        float S = 0.f, SS = 0.f;
        for (int b = 0; b < 64; b++) { S += pS[b * 32 + c]; SS += pSS[b * 32 + c]; }
        const float inv_n = 1.f / (4096.f * 9.f);
        float mean = S * inv_n;
        float var = SS * inv_n - mean * mean;
        float a = bng[c] * rsqrtf(var + 1e-5f);
        stats[c] = a;
        stats[32 + c] = bnb[c] - a * mean;
    }
}

// ---------------------------------------------------------------------------
// Kernel 3: BN-apply + MLP + argmax + 3 selection layers.
// 1024 blocks x 256 threads x 4 examples (4 blocks/CU, 4 waves/SIMD for
// latency hiding). Each wave owns ONE example (eT = tid>>6 wave-uniform);
// selection weights are a single wave-uniform expert stream.
// ---------------------------------------------------------------------------
__global__ __launch_bounds__(256) void mlp_select_kernel(
    const float* __restrict__ out3, const float* __restrict__ stats,
    const float* __restrict__ pw1, const float* __restrict__ pb1,
    const float* __restrict__ pw2, const float* __restrict__ pb2,
    const float* __restrict__ pw3, const float* __restrict__ pb3,
    const float* __restrict__ ew1, const float* __restrict__ eb1,
    const float* __restrict__ ew2, const float* __restrict__ eb2,
    const float* __restrict__ ew3, const float* __restrict__ eb3,
    float* __restrict__ out)
{
    const int tid = threadIdx.x;
    const int img0 = blockIdx.x * 4;

    __shared__ float ysT[288 * 5];    // [j][e], stride 5
    __shared__ float hAT[128 * 5];
    __shared__ float hBT[128 * 5];
    __shared__ float lg[12];
    __shared__ int   acts[4];
    __shared__ float sa[32], sb[32];

    if (tid < 32) { sa[tid] = stats[tid]; sb[tid] = stats[32 + tid]; }
    __syncthreads();

    // stage + BN: 4*72 = 288 float4 reads, scatter-transpose into ysT
    for (int it = 0; it < 2; it++) {
        int i4 = it * 256 + tid;
        if (i4 < 288) {
            int e = i4 / 72, jq = i4 - e * 72;
            float4 v = *(const float4*)&out3[(img0 + e) * 288 + jq * 4];
            int j = jq * 4;
            ysT[(j + 0) * 5 + e] = fmaf(sa[(j + 0) & 31], v.x, sb[(j + 0) & 31]);
            ysT[(j + 1) * 5 + e] = fmaf(sa[(j + 1) & 31], v.y, sb[(j + 1) & 31]);
            ysT[(j + 2) * 5 + e] = fmaf(sa[(j + 2) & 31], v.z, sb[(j + 2) & 31]);
            ysT[(j + 3) * 5 + e] = fmaf(sa[(j + 3) & 31], v.w, sb[(j + 3) & 31]);
        }
    }
    __syncthreads();

    const int n2 = tid & 63, eT = tid >> 6;   // eT wave-uniform

    // layer 1: 288 -> 128, relu
    float acc0 = pb1[n2 * 2], acc1 = pb1[n2 * 2 + 1];
    for (int k = 0; k < 288; k++) {
        int i = (k & 31) * 9 + (k >> 5);
        float2 w = *(const float2*)&pw1[i * 128 + n2 * 2];
        float yv = ysT[k * 5 + eT];
        acc0 = fmaf(yv, w.x, acc0);
        acc1 = fmaf(yv, w.y, acc1);
    }
    hAT[(n2 * 2 + 0) * 5 + eT] = fmaxf(acc0, 0.f);
    hAT[(n2 * 2 + 1) * 5 + eT] = fmaxf(acc1, 0.f);
    __syncthreads();

    // layer 2: 128 -> 128, relu
    acc0 = pb2[n2 * 2]; acc1 = pb2[n2 * 2 + 1];
    for (int k = 0; k < 128; k++) {
        float2 w = *(const float2*)&pw2[k * 128 + n2 * 2];
        float hv = hAT[k * 5 + eT];
        acc0 = fmaf(hv, w.x, acc0);
        acc1 = fmaf(hv, w.y, acc1);
    }
    hBT[(n2 * 2 + 0) * 5 + eT] = fmaxf(acc0, 0.f);
    hBT[(n2 * 2 + 1) * 5 + eT] = fmaxf(acc1, 0.f);
    __syncthreads();

    // logits 128 -> 3, argmax (first-max-wins)
    if (tid < 12) {
        int e = tid / 3, o = tid - e * 3;
        float s = pb3[o];
        for (int k = 0; k < 128; k++) s = fmaf(hBT[k * 5 + e], pw3[k * 3 + o], s);
        lg[e * 3 + o] = s;
    }
    __syncthreads();
    if (tid < 4) {
        float l0 = lg[tid * 3], l1 = lg[tid * 3 + 1], l2 = lg[tid * 3 + 2];
        int a = 0; float best = l0;
        if (l1 > best) { best = l1; a = 1; }
        if (l2 > best) { best = l2; a = 2; }
        acts[tid] = a;
        out[4096 * 10 + img0 + tid] = (float)a;
    }
    __syncthreads();

    const int a = acts[eT];               // wave-uniform expert id

    // selection layer 1: 288 -> 128, single expert stream per wave
    {
        const float* wb = ew1 + a * 36864;
        acc0 = 0.f; acc1 = 0.f;
        for (int k = 0; k < 288; k++) {
            int i = (k & 31) * 9 + (k >> 5);
            float2 w = *(const float2*)&wb[i * 128 + n2 * 2];
            float yv = ysT[k * 5 + eT];
            acc0 = fmaf(yv, w.x, acc0);
            acc1 = fmaf(yv, w.y, acc1);
        }
        hAT[(n2 * 2 + 0) * 5 + eT] = acc0 + eb1[a * 128 + n2 * 2 + 0];
        hAT[(n2 * 2 + 1) * 5 + eT] = acc1 + eb1[a * 128 + n2 * 2 + 1];
    }
    __syncthreads();

    // selection layer 2: 128 -> 128
    {
        const float* wb = ew2 + a * 16384;
        acc0 = 0.f; acc1 = 0.f;
        for (int k = 0; k < 128; k++) {
            float2 w = *(const float2*)&wb[k * 128 + n2 * 2];
            float hv = hAT[k * 5 + eT];
            acc0 = fmaf(hv, w.x, acc0);
            acc1 = fmaf(hv, w.y, acc1);
        }
        hBT[(n2 * 2 + 0) * 5 + eT] = acc0 + eb2[a * 128 + n2 * 2 + 0];
        hBT[(n2 * 2 + 1) * 5 + eT] = acc1 + eb2[a * 128 + n2 * 2 + 1];
    }
    __syncthreads();

    // selection layer 3: 128 -> 10, write final output
    if (tid < 40) {
        int e = tid / 10, o = tid - e * 10;
        int aa = acts[e];
        float s = eb3[aa * 10 + o];
        const float* w3 = &ew3[aa * 1280];
        for (int k = 0; k < 128; k++) s = fmaf(hBT[k * 5 + e], w3[k * 10 + o], s);
        out[(img0 + e) * 10 + o] = s;
    }
}

// ---------------------------------------------------------------------------
extern "C" void kernel_launch(void* const* d_in, const int* in_sizes, int n_in,
                              void* d_out, int out_size, void* d_ws, size_t ws_size,
                              hipStream_t stream)
{
    const float* x   = (const float*)d_in[0];
    const float* cw1 = (const float*)d_in[1];
    const float* cb1 = (const float*)d_in[2];
    const float* cw2 = (const float*)d_in[3];
    const float* cb2 = (const float*)d_in[4];
    const float* cw3 = (const float*)d_in[5];
    const float* cb3 = (const float*)d_in[6];
    const float* bng = (const float*)d_in[7];
    const float* bnb = (const float*)d_in[8];
    const float* pw1 = (const float*)d_in[9];
    const float* pb1 = (const float*)d_in[10];
    const float* pw2 = (const float*)d_in[11];
    const float* pb2 = (const float*)d_in[12];
    const float* pw3 = (const float*)d_in[13];
    const float* pb3 = (const float*)d_in[14];
    const float* ew1 = (const float*)d_in[15];
    const float* eb1 = (const float*)d_in[16];
    const float* ew2 = (const float*)d_in[17];
    const float* eb2 = (const float*)d_in[18];
    const float* ew3 = (const float*)d_in[19];
    const float* eb3 = (const float*)d_in[20];

    float* out     = (float*)d_out;
    float* out3    = (float*)d_ws;                    // 4096*288
    float* pS      = out3 + 4096 * 288;               // 2048
    float* pSS     = pS + 2048;                       // 2048
    float* stats   = pSS + 2048;                      // 64
    float* packed2 = stats + 64;                      // 9216
    float* packed3 = packed2 + 9216;                  // 9216

    repack_kernel<<<72, 256, 0, stream>>>(cw2, cw3, packed2, packed3);
    fused_conv_kernel<<<4096, 256, 0, stream>>>(x, cw1, cb1, packed2, cb2, packed3, cb3, out3);
    bn_part_kernel<<<64, 256, 0, stream>>>(out3, pS, pSS);
    bn_final_kernel<<<1, 64, 0, stream>>>(pS, pSS, bng, bnb, stats);
    mlp_select_kernel<<<1024, 256, 0, stream>>>(out3, stats,
                                                pw1, pb1, pw2, pb2, pw3, pb3,
                                                ew1, eb1, ew2, eb2, ew3, eb3, out);
}

// Round 12
// 453.382 us; speedup vs baseline: 1.2339x; 1.2339x over previous
//
#include <hip/hip_runtime.h>

// ---------------------------------------------------------------------------
// Kernel 0: repack conv2/conv3 weights into [ic*9+tap][oc] linear layout.
// ---------------------------------------------------------------------------
__global__ __launch_bounds__(256) void repack_kernel(
    const float* __restrict__ cw2, const float* __restrict__ cw3,
    float* __restrict__ packed2, float* __restrict__ packed3)
{
    int t = blockIdx.x * 256 + threadIdx.x;   // grid 72*256 = 18432 = 2*9216
    if (t < 9216) {
        int oc = t & 31, r = t >> 5;          // r = ic*9+tap in [0,288)
        packed2[t] = cw2[oc * 288 + r];
    } else {
        int t2 = t - 9216;
        int oc = t2 & 31, r = t2 >> 5;
        packed3[t2] = cw3[oc * 288 + r];
    }
}

// ---------------------------------------------------------------------------
// Kernel 1: fused conv stack, one image per 256-thread block (4 waves).
// LDS 38.4 KB raw (target: 3 blocks/CU under the ~128 KB co-residency budget
// inferred from r9-r11: 2x50=100 ok, 3x46=138 no).
// xs2: 32 planes x 260; rows r*16 with XOR-swizzled col quads:
//   word = plane + r*16 + (((col>>2)+r)&3)*4 + (col&3)
//   -> float4 reads stay 16B-aligned (all terms mult of 4 words; r11's
//      stride-18 broke this and cost 13%); within-wave patch-read collisions
//      only r'/r'+4 pairs = 2-way = free (m136).
// conv2 weights: 4-ic chunks in A (1220 words, union with dead xs1/w1s).
// conv3 weights: 8-ic chunks in B+4160 (dead xs2 space).
// ---------------------------------------------------------------------------
__global__ __launch_bounds__(256)
void fused_conv_kernel(
    const float* __restrict__ x,
    const float* __restrict__ cw1, const float* __restrict__ cb1,
    const float* __restrict__ packed2, const float* __restrict__ cb2,
    const float* __restrict__ packed3, const float* __restrict__ cb3,
    float* __restrict__ out3)
{
    const int img = blockIdx.x;
    const int tid = threadIdx.x;

    __shared__ float A[1220];         // xs1(900)+w1s(288)+b1s(32) | wck2(1152)
    __shared__ float B[8320];         // xs2 (32 x 260) | scratch/xs3/wck3
    __shared__ float b2s[32], b3s[32];

    float* xs1  = A;                  // 900: 30x30 padded image
    float* w1s  = A + 900;            // 288
    float* b1s  = A + 1188;           // 32
    float* wck2 = A;                  // 1152: conv2 4-ic chunk (after conv1)
    float* xs2  = B;                  // 32 planes x 260
    float* sc   = B;                  // reduction scratch head
    float* xs3  = B + 1280;           // 2880: 32 x 90 -> [1280,4160)
    float* wck3 = B + 4160;           // 2304: conv3 8-ic chunk -> [4160,6464)
    float* sc2  = B + 5073;           // pool scratch -> [5102,8320)

    // --- zero xs1 pads + all of B ---
    for (int i = tid; i < 900;  i += 256) xs1[i] = 0.f;
    for (int i = tid; i < 8320; i += 256) B[i] = 0.f;
    __syncthreads();

    // --- stage input image + conv1 weights + biases ---
    for (int i = tid; i < 784; i += 256) {
        int yy = i / 28, xx = i % 28;
        xs1[(yy + 1) * 30 + xx + 1] = x[img * 784 + i];
    }
    for (int i = tid; i < 288; i += 256) {
        int oc = i & 31, tap = i >> 5;
        w1s[i] = cw1[oc * 9 + tap];
    }
    if (tid < 32) { b1s[tid] = cb1[tid]; b2s[tid] = cb2[tid]; b3s[tid] = cb3[tid]; }
    __syncthreads();

    // --- conv1 (1->32) + relu + pool -> xs2 (swizzled) ---
    {
        const int c1 = tid & 31;
        float w1r[9];
        #pragma unroll
        for (int t = 0; t < 9; t++) w1r[t] = w1s[t * 32 + c1];
        const float bias1 = b1s[c1];
        for (int o = tid; o < 32 * 196; o += 256) {
            int p = o >> 5;
            int py = p / 14, px = p % 14;
            int base = (2 * py) * 30 + 2 * px;
            float P[16];
            #pragma unroll
            for (int r = 0; r < 4; r++) {
                float2 u0 = *(const float2*)&xs1[base + r * 30];
                float2 u1 = *(const float2*)&xs1[base + r * 30 + 2];
                P[r * 4 + 0] = u0.x; P[r * 4 + 1] = u0.y;
                P[r * 4 + 2] = u1.x; P[r * 4 + 3] = u1.y;
            }
            float a00 = 0.f, a01 = 0.f, a10 = 0.f, a11 = 0.f;
            #pragma unroll
            for (int ky = 0; ky < 3; ky++)
                #pragma unroll
                for (int kx = 0; kx < 3; kx++) {
                    float w = w1r[ky * 3 + kx];
                    a00 = fmaf(P[ky * 4 + kx],           w, a00);
                    a01 = fmaf(P[ky * 4 + kx + 1],       w, a01);
                    a10 = fmaf(P[(ky + 1) * 4 + kx],     w, a10);
                    a11 = fmaf(P[(ky + 1) * 4 + kx + 1], w, a11);
                }
            float v = fmaxf(fmaxf(fmaxf(a00, a01), fmaxf(a10, a11)) + bias1, 0.f);
            int r = py + 1, col = px + 1;
            xs2[c1 * 260 + r * 16 + ((((col >> 2) + r) & 3) << 2) + (col & 3)] = v;
        }
    }

    // --- conv2: 4oc x 14 cols, K-split-2 over 8 chunks of 4 ic ---
    const int g  = tid >> 7;            // K-group 0..1 (2 waves each)
    const int u  = tid & 127;           // unit; active if u < 112
    const int cb = u & 7, R = u >> 3;   // oc-quad, prepool row 0..13
    const int oc0 = cb * 4;
    const bool act2 = (u < 112);

    float acc[4][14];
    #pragma unroll
    for (int a = 0; a < 4; a++)
        #pragma unroll
        for (int c = 0; c < 14; c++) acc[a][c] = 0.f;

    float pf[5];                        // 1152 = 4.5*256
    #pragma unroll
    for (int k = 0; k < 5; k++) {
        int idx = tid + k * 256;
        pf[k] = (idx < 1152) ? packed2[idx] : 0.f;
    }

    for (int ch = 0; ch < 8; ch++) {
        __syncthreads();                // conv1/xs2 writes + prior wck2 reads done
        #pragma unroll
        for (int k = 0; k < 5; k++) {
            int idx = tid + k * 256;
            if (idx < 1152) wck2[idx] = pf[k];
        }
        if (ch < 7) {
            #pragma unroll
            for (int k = 0; k < 5; k++) {
                int idx = tid + k * 256;
                pf[k] = (idx < 1152) ? packed2[(ch + 1) * 1152 + idx] : 0.f;
            }
        }
        __syncthreads();
        if (act2) {
            #pragma unroll
            for (int d = 0; d < 2; d++) {
                const int ld = g * 2 + d;            // local ic 0..3
                const int ic = ch * 4 + ld;
                const float* wd = &wck2[ld * 288 + oc0];
                const int pb = ic * 260;
                #pragma unroll
                for (int ky = 0; ky < 3; ky++) {
                    const int rp = R + ky;
                    const int rb = pb + rp * 16;
                    float row[16];
                    #pragma unroll
                    for (int q = 0; q < 4; q++) {
                        const float4 t = *(const float4*)&xs2[rb + (((q + rp) & 3) << 2)];
                        row[q * 4 + 0] = t.x; row[q * 4 + 1] = t.y;
                        row[q * 4 + 2] = t.z; row[q * 4 + 3] = t.w;
                    }
                    const float4 wa = *(const float4*)&wd[(ky * 3 + 0) * 32];
                    const float4 wb = *(const float4*)&wd[(ky * 3 + 1) * 32];
                    const float4 wc = *(const float4*)&wd[(ky * 3 + 2) * 32];
                    #pragma unroll
                    for (int c = 0; c < 14; c++) {
                        acc[0][c] = fmaf(row[c],     wa.x, acc[0][c]);
                        acc[1][c] = fmaf(row[c],     wa.y, acc[1][c]);
                        acc[2][c] = fmaf(row[c],     wa.z, acc[2][c]);
                        acc[3][c] = fmaf(row[c],     wa.w, acc[3][c]);
                        acc[0][c] = fmaf(row[c + 1], wb.x, acc[0][c]);
                        acc[1][c] = fmaf(row[c + 1], wb.y, acc[1][c]);
                        acc[2][c] = fmaf(row[c + 1], wb.z, acc[2][c]);
                        acc[3][c] = fmaf(row[c + 1], wb.w, acc[3][c]);
                        acc[0][c] = fmaf(row[c + 2], wc.x, acc[0][c]);
                        acc[1][c] = fmaf(row[c + 2], wc.y, acc[1][c]);
                        acc[2][c] = fmaf(row[c + 2], wc.z, acc[2][c]);
                        acc[3][c] = fmaf(row[c + 2], wc.w, acc[3][c]);
                    }
                }
            }
        }
    }

    // --- conv2 K-reduction (1 round, stride-57 scratch in B head, max 6382) ---
    __syncthreads();                     // all xs2 patch reads done
    if (g == 1 && act2) {
        #pragma unroll
        for (int a = 0; a < 4; a++)
            #pragma unroll
            for (int c = 0; c < 14; c++) sc[u * 57 + a * 14 + c] = acc[a][c];
    }
    __syncthreads();
    if (g == 0 && act2) {
        #pragma unroll
        for (int a = 0; a < 4; a++)
            #pragma unroll
            for (int c = 0; c < 14; c++) acc[a][c] += sc[u * 57 + a * 14 + c];
    }
    __syncthreads();                     // reduction scratch retires

    // --- zero xs3 + pool 14x14->7x7 (register hmax, odd/even R via sc2) ---
    for (int i = tid; i < 2880; i += 256) xs3[i] = 0.f;
    float hm[4][7];
    if (g == 0 && act2) {
        #pragma unroll
        for (int a = 0; a < 4; a++)
            #pragma unroll
            for (int c = 0; c < 7; c++)
                hm[a][c] = fmaxf(acc[a][2 * c], acc[a][2 * c + 1]);
        if (R & 1) {                     // sc2 idx max 111*29+27=3246 -> abs 8319
            #pragma unroll
            for (int a = 0; a < 4; a++)
                #pragma unroll
                for (int c = 0; c < 7; c++) sc2[u * 29 + a * 7 + c] = hm[a][c];
        }
    }
    __syncthreads();
    if (g == 0 && act2 && !(R & 1)) {
        const int py = R >> 1;           // 0..6
        #pragma unroll
        for (int a = 0; a < 4; a++)
            #pragma unroll
            for (int c = 0; c < 7; c++) {
                float v = fmaxf(hm[a][c], sc2[(u + 8) * 29 + a * 7 + c]);
                v = fmaxf(v + b2s[oc0 + a], 0.f);
                xs3[(oc0 + a) * 90 + (py + 1) * 10 + (c + 1)] = v;
            }
    }

    // --- conv3 (32->32, 7x7) + relu + pool(7->3 floor), K-split-2 ---
    const int u3 = tid & 127;
    const bool act3 = (u3 < 72);
    const int cq3 = u3 & 7, pos = u3 >> 3;   // oc-quad, pooled pos 0..8
    const int oc30 = cq3 * 4;
    const int py3 = pos / 3, px3 = pos % 3;
    const int base3 = (2 * py3) * 10 + 2 * px3;

    float a3[4][4];
    #pragma unroll
    for (int a = 0; a < 4; a++)
        #pragma unroll
        for (int q = 0; q < 4; q++) a3[a][q] = 0.f;

    float pg[9];                        // 2304 = 9*256
    #pragma unroll
    for (int k = 0; k < 9; k++) pg[k] = packed3[tid + k * 256];

    for (int ch = 0; ch < 4; ch++) {
        __syncthreads();                 // pool/xs3 writes + prior wck3 reads done
        #pragma unroll
        for (int k = 0; k < 9; k++) wck3[tid + k * 256] = pg[k];
        if (ch < 3) {
            #pragma unroll
            for (int k = 0; k < 9; k++) pg[k] = packed3[(ch + 1) * 2304 + tid + k * 256];
        }
        __syncthreads();
        if (act3) {
            #pragma unroll 2
            for (int d = 0; d < 4; d++) {
                const int ld = g * 4 + d;
                const int ic = ch * 8 + ld;
                const float* xp = &xs3[ic * 90 + base3];
                float P[16];
                #pragma unroll
                for (int r = 0; r < 4; r++) {
                    float2 u0 = *(const float2*)&xp[r * 10];
                    float2 u1 = *(const float2*)&xp[r * 10 + 2];
                    P[r * 4 + 0] = u0.x; P[r * 4 + 1] = u0.y;
                    P[r * 4 + 2] = u1.x; P[r * 4 + 3] = u1.y;
                }
                const float* wd = &wck3[ld * 288 + oc30];
                #pragma unroll
                for (int tap = 0; tap < 9; tap++) {
                    const int ky = tap / 3, kx = tap % 3;
                    const float4 wv = *(const float4*)&wd[tap * 32];
                    const float x00 = P[ky * 4 + kx];
                    const float x01 = P[ky * 4 + kx + 1];
                    const float x10 = P[(ky + 1) * 4 + kx];
                    const float x11 = P[(ky + 1) * 4 + kx + 1];
                    a3[0][0] = fmaf(x00, wv.x, a3[0][0]); a3[0][1] = fmaf(x01, wv.x, a3[0][1]);
                    a3[0][2] = fmaf(x10, wv.x, a3[0][2]); a3[0][3] = fmaf(x11, wv.x, a3[0][3]);
                    a3[1][0] = fmaf(x00, wv.y, a3[1][0]); a3[1][1] = fmaf(x01, wv.y, a3[1][1]);
                    a3[1][2] = fmaf(x10, wv.y, a3[1][2]); a3[1][3] = fmaf(x11, wv.y, a3[1][3]);
                    a3[2][0] = fmaf(x00, wv.z, a3[2][0]); a3[2][1] = fmaf(x01, wv.z, a3[2][1]);
                    a3[2][2] = fmaf(x10, wv.z, a3[2][2]); a3[2][3] = fmaf(x11, wv.z, a3[2][3]);
                    a3[3][0] = fmaf(x00, wv.w, a3[3][0]); a3[3][1] = fmaf(x01, wv.w, a3[3][1]);
                    a3[3][2] = fmaf(x10, wv.w, a3[3][2]); a3[3][3] = fmaf(x11, wv.w, a3[3][3]);
                }
            }
        }
    }

    // --- conv3 K-reduction (1 round, stride-17 scratch in head, max 1222) ---
    __syncthreads();
    if (g == 1 && act3) {
        #pragma unroll
        for (int a = 0; a < 4; a++)
            #pragma unroll
            for (int q = 0; q < 4; q++) sc[u3 * 17 + a * 4 + q] = a3[a][q];
    }
    __syncthreads();
    if (g == 0 && act3) {
        #pragma unroll
        for (int a = 0; a < 4; a++)
            #pragma unroll
            for (int q = 0; q < 4; q++) a3[a][q] += sc[u3 * 17 + a * 4 + q];
        float4 res;
        float* r = (float*)&res;
        #pragma unroll
        for (int a = 0; a < 4; a++) {
            float v = fmaxf(fmaxf(a3[a][0], a3[a][1]), fmaxf(a3[a][2], a3[a][3]));
            r[a] = fmaxf(v + b3s[oc30 + a], 0.f);
        }
        *(float4*)&out3[img * 288 + pos * 32 + oc30] = res;
    }
}

// ---------------------------------------------------------------------------
// Kernel 2a/2b: BatchNorm stats, two-stage
// ---------------------------------------------------------------------------
__global__ __launch_bounds__(256) void bn_part_kernel(
    const float* __restrict__ out3, float* __restrict__ pS, float* __restrict__ pSS)
{
    const int blk = blockIdx.x;                   // 64 blocks
    const int c = threadIdx.x & 31, ml = threadIdx.x >> 5;
    float s = 0.f, ss = 0.f;
    const int base = blk * 576 + ml;
    for (int k = 0; k < 72; k++) {
        float v = out3[(base + k * 8) * 32 + c];  // coalesced
        s += v; ss = fmaf(v, v, ss);
    }
    __shared__ float rs[256], rss[256];
    rs[threadIdx.x] = s; rss[threadIdx.x] = ss;
    __syncthreads();
    if (threadIdx.x < 32) {
        float S = 0.f, SS = 0.f;
        #pragma unroll
        for (int m = 0; m < 8; m++) { S += rs[threadIdx.x + 32 * m]; SS += rss[threadIdx.x + 32 * m]; }
        pS[blk * 32 + threadIdx.x] = S;
        pSS[blk * 32 + threadIdx.x] = SS;
    }
}

__global__ __launch_bounds__(64) void bn_final_kernel(
    const float* __restrict__ pS, const float* __restrict__ pSS,
    const float* __restrict__ bng, const float* __restrict__ bnb,
    float* __restrict__ stats)
{
    int c = threadIdx.x;
    if (c < 32) {
        float S = 0.f, SS = 0.f;
        for (int b = 0; b < 64; b++) { S += pS[b * 32 + c]; SS += pSS[b * 32 + c]; }
        const float inv_n = 1.f / (4096.f * 9.f);
        float mean = S * inv_n;
        float var = SS * inv_n - mean * mean;
        float a = bng[c] * rsqrtf(var + 1e-5f);
        stats[c] = a;
        stats[32 + c] = bnb[c] - a * mean;
    }
}

// ---------------------------------------------------------------------------
// Kernel 3: BN-apply + MLP + argmax + 3 selection layers. (r10 version,
// best measured: ~128 us tail.) 512 blocks x 256 threads x 8 examples; each
// wave serves 2 examples -> 2 wave-uniform expert streams, no selects.
// ---------------------------------------------------------------------------
__global__ __launch_bounds__(256) void mlp_select_kernel(
    const float* __restrict__ out3, const float* __restrict__ stats,
    const float* __restrict__ pw1, const float* __restrict__ pb1,
    const float* __restrict__ pw2, const float* __restrict__ pb2,
    const float* __restrict__ pw3, const float* __restrict__ pb3,
    const float* __restrict__ ew1, const float* __restrict__ eb1,
    const float* __restrict__ ew2, const float* __restrict__ eb2,
    const float* __restrict__ ew3, const float* __restrict__ eb3,
    float* __restrict__ out)
{
    const int tid = threadIdx.x;
    const int img0 = blockIdx.x * 8;

    __shared__ float ysT[288 * 14];   // [j][e], stride 14
    __shared__ float hAT[128 * 14];
    __shared__ float hBT[128 * 14];
    __shared__ float lg[24];
    __shared__ int   acts[8];
    __shared__ float sa[32], sb[32];

    if (tid < 32) { sa[tid] = stats[tid]; sb[tid] = stats[32 + tid]; }
    __syncthreads();

    for (int it = 0; it < 3; it++) {
        int i4 = it * 256 + tid;
        if (i4 < 576) {
            int e = i4 / 72, jq = i4 - e * 72;
            float4 v = *(const float4*)&out3[(img0 + e) * 288 + jq * 4];
            int j = jq * 4;
            ysT[(j + 0) * 14 + e] = fmaf(sa[(j + 0) & 31], v.x, sb[(j + 0) & 31]);
            ysT[(j + 1) * 14 + e] = fmaf(sa[(j + 1) & 31], v.y, sb[(j + 1) & 31]);
            ysT[(j + 2) * 14 + e] = fmaf(sa[(j + 2) & 31], v.z, sb[(j + 2) & 31]);
            ysT[(j + 3) * 14 + e] = fmaf(sa[(j + 3) & 31], v.w, sb[(j + 3) & 31]);
        }
    }
    __syncthreads();

    const int n2 = tid & 63, eT = tid >> 6, e0 = eT * 2;
    float acc[2][2];

    #pragma unroll
    for (int e = 0; e < 2; e++) { acc[e][0] = pb1[n2 * 2]; acc[e][1] = pb1[n2 * 2 + 1]; }
    for (int k = 0; k < 288; k++) {
        int i = (k & 31) * 9 + (k >> 5);
        float2 w = *(const float2*)&pw1[i * 128 + n2 * 2];
        float2 yv = *(const float2*)&ysT[k * 14 + e0];
        acc[0][0] = fmaf(yv.x, w.x, acc[0][0]); acc[0][1] = fmaf(yv.x, w.y, acc[0][1]);
        acc[1][0] = fmaf(yv.y, w.x, acc[1][0]); acc[1][1] = fmaf(yv.y, w.y, acc[1][1]);
    }
    #pragma unroll
    for (int e = 0; e < 2; e++)
        #pragma unroll
        for (int d = 0; d < 2; d++)
            hAT[(n2 * 2 + d) * 14 + e0 + e] = fmaxf(acc[e][d], 0.f);
    __syncthreads();

    #pragma unroll
    for (int e = 0; e < 2; e++) { acc[e][0] = pb2[n2 * 2]; acc[e][1] = pb2[n2 * 2 + 1]; }
    for (int k = 0; k < 128; k++) {
        float2 w = *(const float2*)&pw2[k * 128 + n2 * 2];
        float2 hv = *(const float2*)&hAT[k * 14 + e0];
        acc[0][0] = fmaf(hv.x, w.x, acc[0][0]); acc[0][1] = fmaf(hv.x, w.y, acc[0][1]);
        acc[1][0] = fmaf(hv.y, w.x, acc[1][0]); acc[1][1] = fmaf(hv.y, w.y, acc[1][1]);
    }
    #pragma unroll
    for (int e = 0; e < 2; e++)
        #pragma unroll
        for (int d = 0; d < 2; d++)
            hBT[(n2 * 2 + d) * 14 + e0 + e] = fmaxf(acc[e][d], 0.f);
    __syncthreads();

    if (tid < 24) {
        int e = tid / 3, o = tid - e * 3;
        float s = pb3[o];
        for (int k = 0; k < 128; k++) s = fmaf(hBT[k * 14 + e], pw3[k * 3 + o], s);
        lg[e * 3 + o] = s;
    }
    __syncthreads();
    if (tid < 8) {
        float l0 = lg[tid * 3], l1 = lg[tid * 3 + 1], l2 = lg[tid * 3 + 2];
        int a = 0; float best = l0;
        if (l1 > best) { best = l1; a = 1; }
        if (l2 > best) { best = l2; a = 2; }
        acts[tid] = a;
        out[4096 * 10 + img0 + tid] = (float)a;
    }
    __syncthreads();

    const int a0 = acts[e0], a1 = acts[e0 + 1];   // wave-uniform

    {
        const float* wb0 = ew1 + a0 * 36864;
        const float* wb1 = ew1 + a1 * 36864;
        #pragma unroll
        for (int e = 0; e < 2; e++) { acc[e][0] = 0.f; acc[e][1] = 0.f; }
        for (int k = 0; k < 288; k++) {
            int i = (k & 31) * 9 + (k >> 5);
            float2 wA = *(const float2*)&wb0[i * 128 + n2 * 2];
            float2 wB = *(const float2*)&wb1[i * 128 + n2 * 2];
            float2 yv = *(const float2*)&ysT[k * 14 + e0];
            acc[0][0] = fmaf(yv.x, wA.x, acc[0][0]); acc[0][1] = fmaf(yv.x, wA.y, acc[0][1]);
            acc[1][0] = fmaf(yv.y, wB.x, acc[1][0]); acc[1][1] = fmaf(yv.y, wB.y, acc[1][1]);
        }
        hAT[(n2 * 2 + 0) * 14 + e0 + 0] = acc[0][0] + eb1[a0 * 128 + n2 * 2 + 0];
        hAT[(n2 * 2 + 1) * 14 + e0 + 0] = acc[0][1] + eb1[a0 * 128 + n2 * 2 + 1];
        hAT[(n2 * 2 + 0) * 14 + e0 + 1] = acc[1][0] + eb1[a1 * 128 + n2 * 2 + 0];
        hAT[(n2 * 2 + 1) * 14 + e0 + 1] = acc[1][1] + eb1[a1 * 128 + n2 * 2 + 1];
    }
    __syncthreads();

    {
        const float* wb0 = ew2 + a0 * 16384;
        const float* wb1 = ew2 + a1 * 16384;
        #pragma unroll
        for (int e = 0; e < 2; e++) { acc[e][0] = 0.f; acc[e][1] = 0.f; }
        for (int k = 0; k < 128; k++) {
            float2 wA = *(const float2*)&wb0[k * 128 + n2 * 2];
            float2 wB = *(const float2*)&wb1[k * 128 + n2 * 2];
            float2 hv = *(const float2*)&hAT[k * 14 + e0];
            acc[0][0] = fmaf(hv.x, wA.x, acc[0][0]); acc[0][1] = fmaf(hv.x, wA.y, acc[0][1]);
            acc[1][0] = fmaf(hv.y, wB.x, acc[1][0]); acc[1][1] = fmaf(hv.y, wB.y, acc[1][1]);
        }
        hBT[(n2 * 2 + 0) * 14 + e0 + 0] = acc[0][0] + eb2[a0 * 128 + n2 * 2 + 0];
        hBT[(n2 * 2 + 1) * 14 + e0 + 0] = acc[0][1] + eb2[a0 * 128 + n2 * 2 + 1];
        hBT[(n2 * 2 + 0) * 14 + e0 + 1] = acc[1][0] + eb2[a1 * 128 + n2 * 2 + 0];
        hBT[(n2 * 2 + 1) * 14 + e0 + 1] = acc[1][1] + eb2[a1 * 128 + n2 * 2 + 1];
    }
    __syncthreads();

    if (tid < 80) {
        int e = tid / 10, o = tid - e * 10;
        int a = acts[e];
        float s = eb3[a * 10 + o];
        const float* w3 = &ew3[a * 1280];
        for (int k = 0; k < 128; k++) s = fmaf(hBT[k * 14 + e], w3[k * 10 + o], s);
        out[(img0 + e) * 10 + o] = s;
    }
}

// ---------------------------------------------------------------------------
extern "C" void kernel_launch(void* const* d_in, const int* in_sizes, int n_in,
                              void* d_out, int out_size, void* d_ws, size_t ws_size,
                              hipStream_t stream)
{
    const float* x   = (const float*)d_in[0];
    const float* cw1 = (const float*)d_in[1];
    const float* cb1 = (const float*)d_in[2];
    const float* cw2 = (const float*)d_in[3];
    const float* cb2 = (const float*)d_in[4];
    const float* cw3 = (const float*)d_in[5];
    const float* cb3 = (const float*)d_in[6];
    const float* bng = (const float*)d_in[7];
    const float* bnb = (const float*)d_in[8];
    const float* pw1 = (const float*)d_in[9];
    const float* pb1 = (const float*)d_in[10];
    const float* pw2 = (const float*)d_in[11];
    const float* pb2 = (const float*)d_in[12];
    const float* pw3 = (const float*)d_in[13];
    const float* pb3 = (const float*)d_in[14];
    const float* ew1 = (const float*)d_in[15];
    const float* eb1 = (const float*)d_in[16];
    const float* ew2 = (const float*)d_in[17];
    const float* eb2 = (const float*)d_in[18];
    const float* ew3 = (const float*)d_in[19];
    const float* eb3 = (const float*)d_in[20];

    float* out     = (float*)d_out;
    float* out3    = (float*)d_ws;                    // 4096*288
    float* pS      = out3 + 4096 * 288;               // 2048
    float* pSS     = pS + 2048;                       // 2048
    float* stats   = pSS + 2048;                      // 64
    float* packed2 = stats + 64;                      // 9216
    float* packed3 = packed2 + 9216;                  // 9216

    repack_kernel<<<72, 256, 0, stream>>>(cw2, cw3, packed2, packed3);
    fused_conv_kernel<<<4096, 256, 0, stream>>>(x, cw1, cb1, packed2, cb2, packed3, cb3, out3);
    bn_part_kernel<<<64, 256, 0, stream>>>(out3, pS, pSS);
    bn_final_kernel<<<1, 64, 0, stream>>>(pS, pSS, bng, bnb, stats);
    mlp_select_kernel<<<512, 256, 0, stream>>>(out3, stats,
                                               pw1, pb1, pw2, pb2, pw3, pb3,
                                               ew1, eb1, ew2, eb2, ew3, eb3, out);
}

// Round 13
// 424.819 us; speedup vs baseline: 1.3168x; 1.0672x over previous
//
#include <hip/hip_runtime.h>

// ---------------------------------------------------------------------------
// Kernel 0: repack conv2/conv3 weights into [ic*9+tap][oc] linear layout.
// ---------------------------------------------------------------------------
__global__ __launch_bounds__(256) void repack_kernel(
    const float* __restrict__ cw2, const float* __restrict__ cw3,
    float* __restrict__ packed2, float* __restrict__ packed3)
{
    int t = blockIdx.x * 256 + threadIdx.x;   // grid 72*256 = 18432 = 2*9216
    if (t < 9216) {
        int oc = t & 31, r = t >> 5;          // r = ic*9+tap in [0,288)
        packed2[t] = cw2[oc * 288 + r];
    } else {
        int t2 = t - 9216;
        int oc = t2 & 31, r = t2 >> 5;
        packed3[t2] = cw3[oc * 288 + r];
    }
}

// ---------------------------------------------------------------------------
// Kernel 1: fused conv stack (r12 structure: 38.4 KB LDS, 3 blocks/CU, 82%
// VALUBusy) + fused BatchNorm partial-sum epilogue (replaces bn_part kernel):
// single-writer LDS grid -> 64 atomicAdds/block into gstats[64].
// ---------------------------------------------------------------------------
__global__ __launch_bounds__(256)
void fused_conv_kernel(
    const float* __restrict__ x,
    const float* __restrict__ cw1, const float* __restrict__ cb1,
    const float* __restrict__ packed2, const float* __restrict__ cb2,
    const float* __restrict__ packed3, const float* __restrict__ cb3,
    float* __restrict__ out3, float* __restrict__ gstats)
{
    const int img = blockIdx.x;
    const int tid = threadIdx.x;

    __shared__ float A[1220];         // xs1(900)+w1s(288)+b1s(32) | wck2(1152)
    __shared__ float B[8320];         // xs2 (32 x 260) | scratch/xs3/wck3
    __shared__ float b2s[32], b3s[32];

    float* xs1  = A;                  // 900: 30x30 padded image
    float* w1s  = A + 900;            // 288
    float* b1s  = A + 1188;           // 32
    float* wck2 = A;                  // 1152: conv2 4-ic chunk (after conv1)
    float* xs2  = B;                  // 32 planes x 260
    float* sc   = B;                  // reduction scratch head
    float* xs3  = B + 1280;           // 2880: 32 x 90 -> [1280,4160)
    float* wck3 = B + 4160;           // 2304: conv3 8-ic chunk -> [4160,6464)
    float* sc2  = B + 5073;           // pool scratch -> [5102,8320)

    // --- zero xs1 pads + all of B ---
    for (int i = tid; i < 900;  i += 256) xs1[i] = 0.f;
    for (int i = tid; i < 8320; i += 256) B[i] = 0.f;
    __syncthreads();

    // --- stage input image + conv1 weights + biases ---
    for (int i = tid; i < 784; i += 256) {
        int yy = i / 28, xx = i % 28;
        xs1[(yy + 1) * 30 + xx + 1] = x[img * 784 + i];
    }
    for (int i = tid; i < 288; i += 256) {
        int oc = i & 31, tap = i >> 5;
        w1s[i] = cw1[oc * 9 + tap];
    }
    if (tid < 32) { b1s[tid] = cb1[tid]; b2s[tid] = cb2[tid]; b3s[tid] = cb3[tid]; }
    __syncthreads();

    // --- conv1 (1->32) + relu + pool -> xs2 (swizzled) ---
    {
        const int c1 = tid & 31;
        float w1r[9];
        #pragma unroll
        for (int t = 0; t < 9; t++) w1r[t] = w1s[t * 32 + c1];
        const float bias1 = b1s[c1];
        for (int o = tid; o < 32 * 196; o += 256) {
            int p = o >> 5;
            int py = p / 14, px = p % 14;
            int base = (2 * py) * 30 + 2 * px;
            float P[16];
            #pragma unroll
            for (int r = 0; r < 4; r++) {
                float2 u0 = *(const float2*)&xs1[base + r * 30];
                float2 u1 = *(const float2*)&xs1[base + r * 30 + 2];
                P[r * 4 + 0] = u0.x; P[r * 4 + 1] = u0.y;
                P[r * 4 + 2] = u1.x; P[r * 4 + 3] = u1.y;
            }
            float a00 = 0.f, a01 = 0.f, a10 = 0.f, a11 = 0.f;
            #pragma unroll
            for (int ky = 0; ky < 3; ky++)
                #pragma unroll
                for (int kx = 0; kx < 3; kx++) {
                    float w = w1r[ky * 3 + kx];
                    a00 = fmaf(P[ky * 4 + kx],           w, a00);
                    a01 = fmaf(P[ky * 4 + kx + 1],       w, a01);
                    a10 = fmaf(P[(ky + 1) * 4 + kx],     w, a10);
                    a11 = fmaf(P[(ky + 1) * 4 + kx + 1], w, a11);
                }
            float v = fmaxf(fmaxf(fmaxf(a00, a01), fmaxf(a10, a11)) + bias1, 0.f);
            int r = py + 1, col = px + 1;
            xs2[c1 * 260 + r * 16 + ((((col >> 2) + r) & 3) << 2) + (col & 3)] = v;
        }
    }

    // --- conv2: 4oc x 14 cols, K-split-2 over 8 chunks of 4 ic ---
    const int g  = tid >> 7;            // K-group 0..1 (2 waves each)
    const int u  = tid & 127;           // unit; active if u < 112
    const int cb = u & 7, R = u >> 3;   // oc-quad, prepool row 0..13
    const int oc0 = cb * 4;
    const bool act2 = (u < 112);

    float acc[4][14];
    #pragma unroll
    for (int a = 0; a < 4; a++)
        #pragma unroll
        for (int c = 0; c < 14; c++) acc[a][c] = 0.f;

    float pf[5];                        // 1152 = 4.5*256
    #pragma unroll
    for (int k = 0; k < 5; k++) {
        int idx = tid + k * 256;
        pf[k] = (idx < 1152) ? packed2[idx] : 0.f;
    }

    for (int ch = 0; ch < 8; ch++) {
        __syncthreads();                // conv1/xs2 writes + prior wck2 reads done
        #pragma unroll
        for (int k = 0; k < 5; k++) {
            int idx = tid + k * 256;
            if (idx < 1152) wck2[idx] = pf[k];
        }
        if (ch < 7) {
            #pragma unroll
            for (int k = 0; k < 5; k++) {
                int idx = tid + k * 256;
                pf[k] = (idx < 1152) ? packed2[(ch + 1) * 1152 + idx] : 0.f;
            }
        }
        __syncthreads();
        if (act2) {
            #pragma unroll
            for (int d = 0; d < 2; d++) {
                const int ld = g * 2 + d;            // local ic 0..3
                const int ic = ch * 4 + ld;
                const float* wd = &wck2[ld * 288 + oc0];
                const int pb = ic * 260;
                #pragma unroll
                for (int ky = 0; ky < 3; ky++) {
                    const int rp = R + ky;
                    const int rb = pb + rp * 16;
                    float row[16];
                    #pragma unroll
                    for (int q = 0; q < 4; q++) {
                        const float4 t = *(const float4*)&xs2[rb + (((q + rp) & 3) << 2)];
                        row[q * 4 + 0] = t.x; row[q * 4 + 1] = t.y;
                        row[q * 4 + 2] = t.z; row[q * 4 + 3] = t.w;
                    }
                    const float4 wa = *(const float4*)&wd[(ky * 3 + 0) * 32];
                    const float4 wb = *(const float4*)&wd[(ky * 3 + 1) * 32];
                    const float4 wc = *(const float4*)&wd[(ky * 3 + 2) * 32];
                    #pragma unroll
                    for (int c = 0; c < 14; c++) {
                        acc[0][c] = fmaf(row[c],     wa.x, acc[0][c]);
                        acc[1][c] = fmaf(row[c],     wa.y, acc[1][c]);
                        acc[2][c] = fmaf(row[c],     wa.z, acc[2][c]);
                        acc[3][c] = fmaf(row[c],     wa.w, acc[3][c]);
                        acc[0][c] = fmaf(row[c + 1], wb.x, acc[0][c]);
                        acc[1][c] = fmaf(row[c + 1], wb.y, acc[1][c]);
                        acc[2][c] = fmaf(row[c + 1], wb.z, acc[2][c]);
                        acc[3][c] = fmaf(row[c + 1], wb.w, acc[3][c]);
                        acc[0][c] = fmaf(row[c + 2], wc.x, acc[0][c]);
                        acc[1][c] = fmaf(row[c + 2], wc.y, acc[1][c]);
                        acc[2][c] = fmaf(row[c + 2], wc.z, acc[2][c]);
                        acc[3][c] = fmaf(row[c + 2], wc.w, acc[3][c]);
                    }
                }
            }
        }
    }

    // --- conv2 K-reduction (1 round, stride-57 scratch in B head, max 6382) ---
    __syncthreads();                     // all xs2 patch reads done
    if (g == 1 && act2) {
        #pragma unroll
        for (int a = 0; a < 4; a++)
            #pragma unroll
            for (int c = 0; c < 14; c++) sc[u * 57 + a * 14 + c] = acc[a][c];
    }
    __syncthreads();
    if (g == 0 && act2) {
        #pragma unroll
        for (int a = 0; a < 4; a++)
            #pragma unroll
            for (int c = 0; c < 14; c++) acc[a][c] += sc[u * 57 + a * 14 + c];
    }
    __syncthreads();                     // reduction scratch retires

    // --- zero xs3 + pool 14x14->7x7 (register hmax, odd/even R via sc2) ---
    for (int i = tid; i < 2880; i += 256) xs3[i] = 0.f;
    float hm[4][7];
    if (g == 0 && act2) {
        #pragma unroll
        for (int a = 0; a < 4; a++)
            #pragma unroll
            for (int c = 0; c < 7; c++)
                hm[a][c] = fmaxf(acc[a][2 * c], acc[a][2 * c + 1]);
        if (R & 1) {                     // sc2 idx max 111*29+27=3246 -> abs 8319
            #pragma unroll
            for (int a = 0; a < 4; a++)
                #pragma unroll
                for (int c = 0; c < 7; c++) sc2[u * 29 + a * 7 + c] = hm[a][c];
        }
    }
    __syncthreads();
    if (g == 0 && act2 && !(R & 1)) {
        const int py = R >> 1;           // 0..6
        #pragma unroll
        for (int a = 0; a < 4; a++)
            #pragma unroll
            for (int c = 0; c < 7; c++) {
                float v = fmaxf(hm[a][c], sc2[(u + 8) * 29 + a * 7 + c]);
                v = fmaxf(v + b2s[oc0 + a], 0.f);
                xs3[(oc0 + a) * 90 + (py + 1) * 10 + (c + 1)] = v;
            }
    }

    // --- conv3 (32->32, 7x7) + relu + pool(7->3 floor), K-split-2 ---
    const int u3 = tid & 127;
    const bool act3 = (u3 < 72);
    const int cq3 = u3 & 7, pos = u3 >> 3;   // oc-quad, pooled pos 0..8
    const int oc30 = cq3 * 4;
    const int py3 = pos / 3, px3 = pos % 3;
    const int base3 = (2 * py3) * 10 + 2 * px3;

    float a3[4][4];
    #pragma unroll
    for (int a = 0; a < 4; a++)
        #pragma unroll
        for (int q = 0; q < 4; q++) a3[a][q] = 0.f;

    float pg[9];                        // 2304 = 9*256
    #pragma unroll
    for (int k = 0; k < 9; k++) pg[k] = packed3[tid + k * 256];

    for (int ch = 0; ch < 4; ch++) {
        __syncthreads();                 // pool/xs3 writes + prior wck3 reads done
        #pragma unroll
        for (int k = 0; k < 9; k++) wck3[tid + k * 256] = pg[k];
        if (ch < 3) {
            #pragma unroll
            for (int k = 0; k < 9; k++) pg[k] = packed3[(ch + 1) * 2304 + tid + k * 256];
        }
        __syncthreads();
        if (act3) {
            #pragma unroll 2
            for (int d = 0; d < 4; d++) {
                const int ld = g * 4 + d;
                const int ic = ch * 8 + ld;
                const float* xp = &xs3[ic * 90 + base3];
                float P[16];
                #pragma unroll
                for (int r = 0; r < 4; r++) {
                    float2 u0 = *(const float2*)&xp[r * 10];
                    float2 u1 = *(const float2*)&xp[r * 10 + 2];
                    P[r * 4 + 0] = u0.x; P[r * 4 + 1] = u0.y;
                    P[r * 4 + 2] = u1.x; P[r * 4 + 3] = u1.y;
                }
                const float* wd = &wck3[ld * 288 + oc30];
                #pragma unroll
                for (int tap = 0; tap < 9; tap++) {
                    const int ky = tap / 3, kx = tap % 3;
                    const float4 wv = *(const float4*)&wd[tap * 32];
                    const float x00 = P[ky * 4 + kx];
                    const float x01 = P[ky * 4 + kx + 1];
                    const float x10 = P[(ky + 1) * 4 + kx];
                    const float x11 = P[(ky + 1) * 4 + kx + 1];
                    a3[0][0] = fmaf(x00, wv.x, a3[0][0]); a3[0][1] = fmaf(x01, wv.x, a3[0][1]);
                    a3[0][2] = fmaf(x10, wv.x, a3[0][2]); a3[0][3] = fmaf(x11, wv.x, a3[0][3]);
                    a3[1][0] = fmaf(x00, wv.y, a3[1][0]); a3[1][1] = fmaf(x01, wv.y, a3[1][1]);
                    a3[1][2] = fmaf(x10, wv.y, a3[1][2]); a3[1][3] = fmaf(x11, wv.y, a3[1][3]);
                    a3[2][0] = fmaf(x00, wv.z, a3[2][0]); a3[2][1] = fmaf(x01, wv.z, a3[2][1]);
                    a3[2][2] = fmaf(x10, wv.z, a3[2][2]); a3[2][3] = fmaf(x11, wv.z, a3[2][3]);
                    a3[3][0] = fmaf(x00, wv.w, a3[3][0]); a3[3][1] = fmaf(x01, wv.w, a3[3][1]);
                    a3[3][2] = fmaf(x10, wv.w, a3[3][2]); a3[3][3] = fmaf(x11, wv.w, a3[3][3]);
                }
            }
        }
    }

    // --- conv3 K-reduction (1 round, stride-17 scratch in head, max 1222) ---
    __syncthreads();
    if (g == 1 && act3) {
        #pragma unroll
        for (int a = 0; a < 4; a++)
            #pragma unroll
            for (int q = 0; q < 4; q++) sc[u3 * 17 + a * 4 + q] = a3[a][q];
    }
    __syncthreads();
    float rres[4];
    const bool writer = (g == 0 && act3);
    if (writer) {
        #pragma unroll
        for (int a = 0; a < 4; a++)
            #pragma unroll
            for (int q = 0; q < 4; q++) a3[a][q] += sc[u3 * 17 + a * 4 + q];
        float4 res;
        #pragma unroll
        for (int a = 0; a < 4; a++) {
            float v = fmaxf(fmaxf(a3[a][0], a3[a][1]), fmaxf(a3[a][2], a3[a][3]));
            rres[a] = fmaxf(v + b3s[oc30 + a], 0.f);
        }
        res.x = rres[0]; res.y = rres[1]; res.z = rres[2]; res.w = rres[3];
        *(float4*)&out3[img * 288 + pos * 32 + oc30] = res;
    }

    // --- fused BN partial sums: single-writer LDS grid then 64 atomics ---
    __syncthreads();                     // sc reads done -> B reusable
    for (int i = tid; i < 576; i += 256) B[i] = 0.f;
    __syncthreads();
    if (writer) {
        #pragma unroll
        for (int a = 0; a < 4; a++) {
            B[pos * 64 + oc30 + a]      = rres[a];
            B[pos * 64 + 32 + oc30 + a] = rres[a] * rres[a];
        }
    }
    __syncthreads();
    if (tid < 64) {
        int c = tid & 31, part = tid >> 5;   // part 0 = S, 1 = SS
        float s = 0.f;
        #pragma unroll
        for (int p = 0; p < 9; p++) s += B[p * 64 + part * 32 + c];
        atomicAdd(&gstats[part * 32 + c], s);
    }
}

// ---------------------------------------------------------------------------
// Kernel 2: BatchNorm finalize from atomic partial sums.
// ---------------------------------------------------------------------------
__global__ __launch_bounds__(64) void bn_final_kernel(
    const float* __restrict__ gstats,
    const float* __restrict__ bng, const float* __restrict__ bnb,
    float* __restrict__ stats)
{
    int c = threadIdx.x;
    if (c < 32) {
        float S = gstats[c];
        float SS = gstats[32 + c];
        const float inv_n = 1.f / (4096.f * 9.f);
        float mean = S * inv_n;
        float var = SS * inv_n - mean * mean;
        float a = bng[c] * rsqrtf(var + 1e-5f);
        stats[c] = a;
        stats[32 + c] = bnb[c] - a * mean;
    }
}

// ---------------------------------------------------------------------------
// Kernel 3: BN-apply + MLP + argmax + 3 selection layers.
// 512 blocks x 256 threads x 8 examples. Thread = (n4 = tid&31 -> 4 neurons,
// float4 weight loads) x (eE = tid>>5 -> ONE example). Wave = 2 examples as
// half-waves; dup addresses across halves coalesce, so bytes/wave match r10
// while global load instrs drop 1248 -> 832 per thread. Expert stream is
// half-wave-uniform -> single stream per thread, no selects.
// ---------------------------------------------------------------------------
__global__ __launch_bounds__(256) void mlp_select_kernel(
    const float* __restrict__ out3, const float* __restrict__ stats,
    const float* __restrict__ pw1, const float* __restrict__ pb1,
    const float* __restrict__ pw2, const float* __restrict__ pb2,
    const float* __restrict__ pw3, const float* __restrict__ pb3,
    const float* __restrict__ ew1, const float* __restrict__ eb1,
    const float* __restrict__ ew2, const float* __restrict__ eb2,
    const float* __restrict__ ew3, const float* __restrict__ eb3,
    float* __restrict__ out)
{
    const int tid = threadIdx.x;
    const int img0 = blockIdx.x * 8;

    __shared__ float ysT[288 * 14];   // [j][e], stride 14
    __shared__ float hAT[128 * 14];
    __shared__ float hBT[128 * 14];
    __shared__ float lg[24];
    __shared__ int   acts[8];
    __shared__ float sa[32], sb[32];

    if (tid < 32) { sa[tid] = stats[tid]; sb[tid] = stats[32 + tid]; }
    __syncthreads();

    // stage + BN: 8*72 = 576 float4 reads, scatter-transpose into ysT
    for (int it = 0; it < 3; it++) {
        int i4 = it * 256 + tid;
        if (i4 < 576) {
            int e = i4 / 72, jq = i4 - e * 72;
            float4 v = *(const float4*)&out3[(img0 + e) * 288 + jq * 4];
            int j = jq * 4;
            ysT[(j + 0) * 14 + e] = fmaf(sa[(j + 0) & 31], v.x, sb[(j + 0) & 31]);
            ysT[(j + 1) * 14 + e] = fmaf(sa[(j + 1) & 31], v.y, sb[(j + 1) & 31]);
            ysT[(j + 2) * 14 + e] = fmaf(sa[(j + 2) & 31], v.z, sb[(j + 2) & 31]);
            ysT[(j + 3) * 14 + e] = fmaf(sa[(j + 3) & 31], v.w, sb[(j + 3) & 31]);
        }
    }
    __syncthreads();

    const int n4 = tid & 31;          // neuron quad: n = n4*4 .. n4*4+3
    const int eE = tid >> 5;          // example 0..7 (half-wave uniform)
    float acc[4];

    // layer 1: 288 -> 128, relu
    {
        float4 b = *(const float4*)&pb1[n4 * 4];
        acc[0] = b.x; acc[1] = b.y; acc[2] = b.z; acc[3] = b.w;
        for (int k = 0; k < 288; k++) {
            int i = (k & 31) * 9 + (k >> 5);
            float4 w = *(const float4*)&pw1[i * 128 + n4 * 4];
            float yv = ysT[k * 14 + eE];
            acc[0] = fmaf(yv, w.x, acc[0]); acc[1] = fmaf(yv, w.y, acc[1]);
            acc[2] = fmaf(yv, w.z, acc[2]); acc[3] = fmaf(yv, w.w, acc[3]);
        }
        #pragma unroll
        for (int j = 0; j < 4; j++)
            hAT[(n4 * 4 + j) * 14 + eE] = fmaxf(acc[j], 0.f);
    }
    __syncthreads();

    // layer 2: 128 -> 128, relu
    {
        float4 b = *(const float4*)&pb2[n4 * 4];
        acc[0] = b.x; acc[1] = b.y; acc[2] = b.z; acc[3] = b.w;
        for (int k = 0; k < 128; k++) {
            float4 w = *(const float4*)&pw2[k * 128 + n4 * 4];
            float hv = hAT[k * 14 + eE];
            acc[0] = fmaf(hv, w.x, acc[0]); acc[1] = fmaf(hv, w.y, acc[1]);
            acc[2] = fmaf(hv, w.z, acc[2]); acc[3] = fmaf(hv, w.w, acc[3]);
        }
        #pragma unroll
        for (int j = 0; j < 4; j++)
            hBT[(n4 * 4 + j) * 14 + eE] = fmaxf(acc[j], 0.f);
    }
    __syncthreads();

    // logits 128 -> 3, argmax (first-max-wins)
    if (tid < 24) {
        int e = tid / 3, o = tid - e * 3;
        float s = pb3[o];
        for (int k = 0; k < 128; k++) s = fmaf(hBT[k * 14 + e], pw3[k * 3 + o], s);
        lg[e * 3 + o] = s;
    }
    __syncthreads();
    if (tid < 8) {
        float l0 = lg[tid * 3], l1 = lg[tid * 3 + 1], l2 = lg[tid * 3 + 2];
        int a = 0; float best = l0;
        if (l1 > best) { best = l1; a = 1; }
        if (l2 > best) { best = l2; a = 2; }
        acts[tid] = a;
        out[4096 * 10 + img0 + tid] = (float)a;
    }
    __syncthreads();

    const int a = acts[eE];           // half-wave-uniform expert id

    // selection layer 1: 288 -> 128, single expert stream
    {
        const float* wb = ew1 + a * 36864;
        acc[0] = 0.f; acc[1] = 0.f; acc[2] = 0.f; acc[3] = 0.f;
        for (int k = 0; k < 288; k++) {
            int i = (k & 31) * 9 + (k >> 5);
            float4 w = *(const float4*)&wb[i * 128 + n4 * 4];
            float yv = ysT[k * 14 + eE];
            acc[0] = fmaf(yv, w.x, acc[0]); acc[1] = fmaf(yv, w.y, acc[1]);
            acc[2] = fmaf(yv, w.z, acc[2]); acc[3] = fmaf(yv, w.w, acc[3]);
        }
        float4 b = *(const float4*)&eb1[a * 128 + n4 * 4];
        hAT[(n4 * 4 + 0) * 14 + eE] = acc[0] + b.x;
        hAT[(n4 * 4 + 1) * 14 + eE] = acc[1] + b.y;
        hAT[(n4 * 4 + 2) * 14 + eE] = acc[2] + b.z;
        hAT[(n4 * 4 + 3) * 14 + eE] = acc[3] + b.w;
    }
    __syncthreads();

    // selection layer 2: 128 -> 128
    {
        const float* wb = ew2 + a * 16384;
        acc[0] = 0.f; acc[1] = 0.f; acc[2] = 0.f; acc[3] = 0.f;
        for (int k = 0; k < 128; k++) {
            float4 w = *(const float4*)&wb[k * 128 + n4 * 4];
            float hv = hAT[k * 14 + eE];
            acc[0] = fmaf(hv, w.x, acc[0]); acc[1] = fmaf(hv, w.y, acc[1]);
            acc[2] = fmaf(hv, w.z, acc[2]); acc[3] = fmaf(hv, w.w, acc[3]);
        }
        float4 b = *(const float4*)&eb2[a * 128 + n4 * 4];
        hBT[(n4 * 4 + 0) * 14 + eE] = acc[0] + b.x;
        hBT[(n4 * 4 + 1) * 14 + eE] = acc[1] + b.y;
        hBT[(n4 * 4 + 2) * 14 + eE] = acc[2] + b.z;
        hBT[(n4 * 4 + 3) * 14 + eE] = acc[3] + b.w;
    }
    __syncthreads();

    // selection layer 3: 128 -> 10, write final output
    if (tid < 80) {
        int e = tid / 10, o = tid - e * 10;
        int aa = acts[e];
        float s = eb3[aa * 10 + o];
        const float* w3 = &ew3[aa * 1280];
        for (int k = 0; k < 128; k++) s = fmaf(hBT[k * 14 + e], w3[k * 10 + o], s);
        out[(img0 + e) * 10 + o] = s;
    }
}

// ---------------------------------------------------------------------------
extern "C" void kernel_launch(void* const* d_in, const int* in_sizes, int n_in,
                              void* d_out, int out_size, void* d_ws, size_t ws_size,
                              hipStream_t stream)
{
    const float* x   = (const float*)d_in[0];
    const float* cw1 = (const float*)d_in[1];
    const float* cb1 = (const float*)d_in[2];
    const float* cw2 = (const float*)d_in[3];
    const float* cb2 = (const float*)d_in[4];
    const float* cw3 = (const float*)d_in[5];
    const float* cb3 = (const float*)d_in[6];
    const float* bng = (const float*)d_in[7];
    const float* bnb = (const float*)d_in[8];
    const float* pw1 = (const float*)d_in[9];
    const float* pb1 = (const float*)d_in[10];
    const float* pw2 = (const float*)d_in[11];
    const float* pb2 = (const float*)d_in[12];
    const float* pw3 = (const float*)d_in[13];
    const float* pb3 = (const float*)d_in[14];
    const float* ew1 = (const float*)d_in[15];
    const float* eb1 = (const float*)d_in[16];
    const float* ew2 = (const float*)d_in[17];
    const float* eb2 = (const float*)d_in[18];
    const float* ew3 = (const float*)d_in[19];
    const float* eb3 = (const float*)d_in[20];

    float* out     = (float*)d_out;
    float* out3    = (float*)d_ws;                    // 4096*288
    float* gstats  = out3 + 4096 * 288;               // 64 (atomic S/SS)
    float* stats   = gstats + 64;                     // 64 (scale/shift)
    float* packed2 = stats + 64;                      // 9216
    float* packed3 = packed2 + 9216;                  // 9216

    hipMemsetAsync(gstats, 0, 64 * sizeof(float), stream);
    repack_kernel<<<72, 256, 0, stream>>>(cw2, cw3, packed2, packed3);
    fused_conv_kernel<<<4096, 256, 0, stream>>>(x, cw1, cb1, packed2, cb2,
                                                packed3, cb3, out3, gstats);
    bn_final_kernel<<<1, 64, 0, stream>>>(gstats, bng, bnb, stats);
    mlp_select_kernel<<<512, 256, 0, stream>>>(out3, stats,
                                               pw1, pb1, pw2, pb2, pw3, pb3,
                                               ew1, eb1, ew2, eb2, ew3, eb3, out);
}

// Round 14
// 420.289 us; speedup vs baseline: 1.3310x; 1.0108x over previous
//
#include <hip/hip_runtime.h>

// ---------------------------------------------------------------------------
// Kernel 0: repack conv2/conv3 weights into [ic*9+tap][oc] linear layout.
// ---------------------------------------------------------------------------
__global__ __launch_bounds__(256) void repack_kernel(
    const float* __restrict__ cw2, const float* __restrict__ cw3,
    float* __restrict__ packed2, float* __restrict__ packed3)
{
    int t = blockIdx.x * 256 + threadIdx.x;   // grid 72*256 = 18432 = 2*9216
    if (t < 9216) {
        int oc = t & 31, r = t >> 5;          // r = ic*9+tap in [0,288)
        packed2[t] = cw2[oc * 288 + r];
    } else {
        int t2 = t - 9216;
        int oc = t2 & 31, r = t2 >> 5;
        packed3[t2] = cw3[oc * 288 + r];
    }
}

// ---------------------------------------------------------------------------
// Kernel 1: fused conv stack (r12 structure: 38.4 KB LDS, 3 blocks/CU, ~81%
// VALUBusy) + fused BatchNorm partial-sum epilogue -> gstats[64] atomics.
// ---------------------------------------------------------------------------
__global__ __launch_bounds__(256)
void fused_conv_kernel(
    const float* __restrict__ x,
    const float* __restrict__ cw1, const float* __restrict__ cb1,
    const float* __restrict__ packed2, const float* __restrict__ cb2,
    const float* __restrict__ packed3, const float* __restrict__ cb3,
    float* __restrict__ out3, float* __restrict__ gstats)
{
    const int img = blockIdx.x;
    const int tid = threadIdx.x;

    __shared__ float A[1220];         // xs1(900)+w1s(288)+b1s(32) | wck2(1152)
    __shared__ float B[8320];         // xs2 (32 x 260) | scratch/xs3/wck3
    __shared__ float b2s[32], b3s[32];

    float* xs1  = A;                  // 900: 30x30 padded image
    float* w1s  = A + 900;            // 288
    float* b1s  = A + 1188;           // 32
    float* wck2 = A;                  // 1152: conv2 4-ic chunk (after conv1)
    float* xs2  = B;                  // 32 planes x 260
    float* sc   = B;                  // reduction scratch head
    float* xs3  = B + 1280;           // 2880: 32 x 90 -> [1280,4160)
    float* wck3 = B + 4160;           // 2304: conv3 8-ic chunk -> [4160,6464)
    float* sc2  = B + 5073;           // pool scratch -> [5102,8320)

    // --- zero xs1 pads + all of B ---
    for (int i = tid; i < 900;  i += 256) xs1[i] = 0.f;
    for (int i = tid; i < 8320; i += 256) B[i] = 0.f;
    __syncthreads();

    // --- stage input image + conv1 weights + biases ---
    for (int i = tid; i < 784; i += 256) {
        int yy = i / 28, xx = i % 28;
        xs1[(yy + 1) * 30 + xx + 1] = x[img * 784 + i];
    }
    for (int i = tid; i < 288; i += 256) {
        int oc = i & 31, tap = i >> 5;
        w1s[i] = cw1[oc * 9 + tap];
    }
    if (tid < 32) { b1s[tid] = cb1[tid]; b2s[tid] = cb2[tid]; b3s[tid] = cb3[tid]; }
    __syncthreads();

    // --- conv1 (1->32) + relu + pool -> xs2 (swizzled) ---
    {
        const int c1 = tid & 31;
        float w1r[9];
        #pragma unroll
        for (int t = 0; t < 9; t++) w1r[t] = w1s[t * 32 + c1];
        const float bias1 = b1s[c1];
        for (int o = tid; o < 32 * 196; o += 256) {
            int p = o >> 5;
            int py = p / 14, px = p % 14;
            int base = (2 * py) * 30 + 2 * px;
            float P[16];
            #pragma unroll
            for (int r = 0; r < 4; r++) {
                float2 u0 = *(const float2*)&xs1[base + r * 30];
                float2 u1 = *(const float2*)&xs1[base + r * 30 + 2];
                P[r * 4 + 0] = u0.x; P[r * 4 + 1] = u0.y;
                P[r * 4 + 2] = u1.x; P[r * 4 + 3] = u1.y;
            }
            float a00 = 0.f, a01 = 0.f, a10 = 0.f, a11 = 0.f;
            #pragma unroll
            for (int ky = 0; ky < 3; ky++)
                #pragma unroll
                for (int kx = 0; kx < 3; kx++) {
                    float w = w1r[ky * 3 + kx];
                    a00 = fmaf(P[ky * 4 + kx],           w, a00);
                    a01 = fmaf(P[ky * 4 + kx + 1],       w, a01);
                    a10 = fmaf(P[(ky + 1) * 4 + kx],     w, a10);
                    a11 = fmaf(P[(ky + 1) * 4 + kx + 1], w, a11);
                }
            float v = fmaxf(fmaxf(fmaxf(a00, a01), fmaxf(a10, a11)) + bias1, 0.f);
            int r = py + 1, col = px + 1;
            xs2[c1 * 260 + r * 16 + ((((col >> 2) + r) & 3) << 2) + (col & 3)] = v;
        }
    }

    // --- conv2: 4oc x 14 cols, K-split-2 over 8 chunks of 4 ic ---
    const int g  = tid >> 7;            // K-group 0..1 (2 waves each)
    const int u  = tid & 127;           // unit; active if u < 112
    const int cb = u & 7, R = u >> 3;   // oc-quad, prepool row 0..13
    const int oc0 = cb * 4;
    const bool act2 = (u < 112);

    float acc[4][14];
    #pragma unroll
    for (int a = 0; a < 4; a++)
        #pragma unroll
        for (int c = 0; c < 14; c++) acc[a][c] = 0.f;

    float pf[5];                        // 1152 = 4.5*256
    #pragma unroll
    for (int k = 0; k < 5; k++) {
        int idx = tid + k * 256;
        pf[k] = (idx < 1152) ? packed2[idx] : 0.f;
    }

    for (int ch = 0; ch < 8; ch++) {
        __syncthreads();                // conv1/xs2 writes + prior wck2 reads done
        #pragma unroll
        for (int k = 0; k < 5; k++) {
            int idx = tid + k * 256;
            if (idx < 1152) wck2[idx] = pf[k];
        }
        if (ch < 7) {
            #pragma unroll
            for (int k = 0; k < 5; k++) {
                int idx = tid + k * 256;
                pf[k] = (idx < 1152) ? packed2[(ch + 1) * 1152 + idx] : 0.f;
            }
        }
        __syncthreads();
        if (act2) {
            #pragma unroll
            for (int d = 0; d < 2; d++) {
                const int ld = g * 2 + d;            // local ic 0..3
                const int ic = ch * 4 + ld;
                const float* wd = &wck2[ld * 288 + oc0];
                const int pb = ic * 260;
                #pragma unroll
                for (int ky = 0; ky < 3; ky++) {
                    const int rp = R + ky;
                    const int rb = pb + rp * 16;
                    float row[16];
                    #pragma unroll
                    for (int q = 0; q < 4; q++) {
                        const float4 t = *(const float4*)&xs2[rb + (((q + rp) & 3) << 2)];
                        row[q * 4 + 0] = t.x; row[q * 4 + 1] = t.y;
                        row[q * 4 + 2] = t.z; row[q * 4 + 3] = t.w;
                    }
                    const float4 wa = *(const float4*)&wd[(ky * 3 + 0) * 32];
                    const float4 wb = *(const float4*)&wd[(ky * 3 + 1) * 32];
                    const float4 wc = *(const float4*)&wd[(ky * 3 + 2) * 32];
                    #pragma unroll
                    for (int c = 0; c < 14; c++) {
                        acc[0][c] = fmaf(row[c],     wa.x, acc[0][c]);
                        acc[1][c] = fmaf(row[c],     wa.y, acc[1][c]);
                        acc[2][c] = fmaf(row[c],     wa.z, acc[2][c]);
                        acc[3][c] = fmaf(row[c],     wa.w, acc[3][c]);
                        acc[0][c] = fmaf(row[c + 1], wb.x, acc[0][c]);
                        acc[1][c] = fmaf(row[c + 1], wb.y, acc[1][c]);
                        acc[2][c] = fmaf(row[c + 1], wb.z, acc[2][c]);
                        acc[3][c] = fmaf(row[c + 1], wb.w, acc[3][c]);
                        acc[0][c] = fmaf(row[c + 2], wc.x, acc[0][c]);
                        acc[1][c] = fmaf(row[c + 2], wc.y, acc[1][c]);
                        acc[2][c] = fmaf(row[c + 2], wc.z, acc[2][c]);
                        acc[3][c] = fmaf(row[c + 2], wc.w, acc[3][c]);
                    }
                }
            }
        }
    }

    // --- conv2 K-reduction (1 round, stride-57 scratch in B head, max 6382) ---
    __syncthreads();                     // all xs2 patch reads done
    if (g == 1 && act2) {
        #pragma unroll
        for (int a = 0; a < 4; a++)
            #pragma unroll
            for (int c = 0; c < 14; c++) sc[u * 57 + a * 14 + c] = acc[a][c];
    }
    __syncthreads();
    if (g == 0 && act2) {
        #pragma unroll
        for (int a = 0; a < 4; a++)
            #pragma unroll
            for (int c = 0; c < 14; c++) acc[a][c] += sc[u * 57 + a * 14 + c];
    }
    __syncthreads();                     // reduction scratch retires

    // --- zero xs3 + pool 14x14->7x7 (register hmax, odd/even R via sc2) ---
    for (int i = tid; i < 2880; i += 256) xs3[i] = 0.f;
    float hm[4][7];
    if (g == 0 && act2) {
        #pragma unroll
        for (int a = 0; a < 4; a++)
            #pragma unroll
            for (int c = 0; c < 7; c++)
                hm[a][c] = fmaxf(acc[a][2 * c], acc[a][2 * c + 1]);
        if (R & 1) {                     // sc2 idx max 111*29+27=3246 -> abs 8319
            #pragma unroll
            for (int a = 0; a < 4; a++)
                #pragma unroll
                for (int c = 0; c < 7; c++) sc2[u * 29 + a * 7 + c] = hm[a][c];
        }
    }
    __syncthreads();
    if (g == 0 && act2 && !(R & 1)) {
        const int py = R >> 1;           // 0..6
        #pragma unroll
        for (int a = 0; a < 4; a++)
            #pragma unroll
            for (int c = 0; c < 7; c++) {
                float v = fmaxf(hm[a][c], sc2[(u + 8) * 29 + a * 7 + c]);
                v = fmaxf(v + b2s[oc0 + a], 0.f);
                xs3[(oc0 + a) * 90 + (py + 1) * 10 + (c + 1)] = v;
            }
    }

    // --- conv3 (32->32, 7x7) + relu + pool(7->3 floor), K-split-2 ---
    const int u3 = tid & 127;
    const bool act3 = (u3 < 72);
    const int cq3 = u3 & 7, pos = u3 >> 3;   // oc-quad, pooled pos 0..8
    const int oc30 = cq3 * 4;
    const int py3 = pos / 3, px3 = pos % 3;
    const int base3 = (2 * py3) * 10 + 2 * px3;

    float a3[4][4];
    #pragma unroll
    for (int a = 0; a < 4; a++)
        #pragma unroll
        for (int q = 0; q < 4; q++) a3[a][q] = 0.f;

    float pg[9];                        // 2304 = 9*256
    #pragma unroll
    for (int k = 0; k < 9; k++) pg[k] = packed3[tid + k * 256];

    for (int ch = 0; ch < 4; ch++) {
        __syncthreads();                 // pool/xs3 writes + prior wck3 reads done
        #pragma unroll
        for (int k = 0; k < 9; k++) wck3[tid + k * 256] = pg[k];
        if (ch < 3) {
            #pragma unroll
            for (int k = 0; k < 9; k++) pg[k] = packed3[(ch + 1) * 2304 + tid + k * 256];
        }
        __syncthreads();
        if (act3) {
            #pragma unroll 2
            for (int d = 0; d < 4; d++) {
                const int ld = g * 4 + d;
                const int ic = ch * 8 + ld;
                const float* xp = &xs3[ic * 90 + base3];
                float P[16];
                #pragma unroll
                for (int r = 0; r < 4; r++) {
                    float2 u0 = *(const float2*)&xp[r * 10];
                    float2 u1 = *(const float2*)&xp[r * 10 + 2];
                    P[r * 4 + 0] = u0.x; P[r * 4 + 1] = u0.y;
                    P[r * 4 + 2] = u1.x; P[r * 4 + 3] = u1.y;
                }
                const float* wd = &wck3[ld * 288 + oc30];
                #pragma unroll
                for (int tap = 0; tap < 9; tap++) {
                    const int ky = tap / 3, kx = tap % 3;
                    const float4 wv = *(const float4*)&wd[tap * 32];
                    const float x00 = P[ky * 4 + kx];
                    const float x01 = P[ky * 4 + kx + 1];
                    const float x10 = P[(ky + 1) * 4 + kx];
                    const float x11 = P[(ky + 1) * 4 + kx + 1];
                    a3[0][0] = fmaf(x00, wv.x, a3[0][0]); a3[0][1] = fmaf(x01, wv.x, a3[0][1]);
                    a3[0][2] = fmaf(x10, wv.x, a3[0][2]); a3[0][3] = fmaf(x11, wv.x, a3[0][3]);
                    a3[1][0] = fmaf(x00, wv.y, a3[1][0]); a3[1][1] = fmaf(x01, wv.y, a3[1][1]);
                    a3[1][2] = fmaf(x10, wv.y, a3[1][2]); a3[1][3] = fmaf(x11, wv.y, a3[1][3]);
                    a3[2][0] = fmaf(x00, wv.z, a3[2][0]); a3[2][1] = fmaf(x01, wv.z, a3[2][1]);
                    a3[2][2] = fmaf(x10, wv.z, a3[2][2]); a3[2][3] = fmaf(x11, wv.z, a3[2][3]);
                    a3[3][0] = fmaf(x00, wv.w, a3[3][0]); a3[3][1] = fmaf(x01, wv.w, a3[3][1]);
                    a3[3][2] = fmaf(x10, wv.w, a3[3][2]); a3[3][3] = fmaf(x11, wv.w, a3[3][3]);
                }
            }
        }
    }

    // --- conv3 K-reduction (1 round, stride-17 scratch in head, max 1222) ---
    __syncthreads();
    if (g == 1 && act3) {
        #pragma unroll
        for (int a = 0; a < 4; a++)
            #pragma unroll
            for (int q = 0; q < 4; q++) sc[u3 * 17 + a * 4 + q] = a3[a][q];
    }
    __syncthreads();
    float rres[4];
    const bool writer = (g == 0 && act3);
    if (writer) {
        #pragma unroll
        for (int a = 0; a < 4; a++)
            #pragma unroll
            for (int q = 0; q < 4; q++) a3[a][q] += sc[u3 * 17 + a * 4 + q];
        float4 res;
        #pragma unroll
        for (int a = 0; a < 4; a++) {
            float v = fmaxf(fmaxf(a3[a][0], a3[a][1]), fmaxf(a3[a][2], a3[a][3]));
            rres[a] = fmaxf(v + b3s[oc30 + a], 0.f);
        }
        res.x = rres[0]; res.y = rres[1]; res.z = rres[2]; res.w = rres[3];
        *(float4*)&out3[img * 288 + pos * 32 + oc30] = res;
    }

    // --- fused BN partial sums: single-writer LDS grid then 64 atomics ---
    __syncthreads();                     // sc reads done -> B reusable
    for (int i = tid; i < 576; i += 256) B[i] = 0.f;
    __syncthreads();
    if (writer) {
        #pragma unroll
        for (int a = 0; a < 4; a++) {
            B[pos * 64 + oc30 + a]      = rres[a];
            B[pos * 64 + 32 + oc30 + a] = rres[a] * rres[a];
        }
    }
    __syncthreads();
    if (tid < 64) {
        int c = tid & 31, part = tid >> 5;   // part 0 = S, 1 = SS
        float s = 0.f;
        #pragma unroll
        for (int p = 0; p < 9; p++) s += B[p * 64 + part * 32 + c];
        atomicAdd(&gstats[part * 32 + c], s);
    }
}

// ---------------------------------------------------------------------------
// Kernel 3: BN-finalize (folded, redundant per block) + BN-apply + MLP +
// argmax + 3 selection layers. 512 blocks x 256 threads x 8 examples.
// Thread = (n4 = tid&31 -> 4 neurons, float4 loads) x (eE = tid>>5 -> 1
// example; half-wave-uniform expert stream). Logits and sel3 parallelized
// into 2 K-partials each (48 / 160 threads instead of 24 / 80 serial).
// ---------------------------------------------------------------------------
__global__ __launch_bounds__(256) void mlp_select_kernel(
    const float* __restrict__ out3, const float* __restrict__ gstats,
    const float* __restrict__ bng, const float* __restrict__ bnb,
    const float* __restrict__ pw1, const float* __restrict__ pb1,
    const float* __restrict__ pw2, const float* __restrict__ pb2,
    const float* __restrict__ pw3, const float* __restrict__ pb3,
    const float* __restrict__ ew1, const float* __restrict__ eb1,
    const float* __restrict__ ew2, const float* __restrict__ eb2,
    const float* __restrict__ ew3, const float* __restrict__ eb3,
    float* __restrict__ out)
{
    const int tid = threadIdx.x;
    const int img0 = blockIdx.x * 8;

    __shared__ float ysT[288 * 14];   // [j][e], stride 14
    __shared__ float hAT[128 * 14];
    __shared__ float hBT[128 * 14];
    __shared__ float lgp[48];
    __shared__ float sp[160];
    __shared__ int   acts[8];
    __shared__ float sa[32], sb[32];

    // BN finalize from global atomic sums (redundant per block; ~free)
    if (tid < 32) {
        float S = gstats[tid], SS = gstats[32 + tid];
        const float inv_n = 1.f / (4096.f * 9.f);
        float mean = S * inv_n;
        float var = SS * inv_n - mean * mean;
        float a = bng[tid] * rsqrtf(var + 1e-5f);
        sa[tid] = a;
        sb[tid] = bnb[tid] - a * mean;
    }
    __syncthreads();

    // stage + BN: 8*72 = 576 float4 reads, scatter-transpose into ysT
    for (int it = 0; it < 3; it++) {
        int i4 = it * 256 + tid;
        if (i4 < 576) {
            int e = i4 / 72, jq = i4 - e * 72;
            float4 v = *(const float4*)&out3[(img0 + e) * 288 + jq * 4];
            int j = jq * 4;
            ysT[(j + 0) * 14 + e] = fmaf(sa[(j + 0) & 31], v.x, sb[(j + 0) & 31]);
            ysT[(j + 1) * 14 + e] = fmaf(sa[(j + 1) & 31], v.y, sb[(j + 1) & 31]);
            ysT[(j + 2) * 14 + e] = fmaf(sa[(j + 2) & 31], v.z, sb[(j + 2) & 31]);
            ysT[(j + 3) * 14 + e] = fmaf(sa[(j + 3) & 31], v.w, sb[(j + 3) & 31]);
        }
    }
    __syncthreads();

    const int n4 = tid & 31;          // neuron quad: n = n4*4 .. n4*4+3
    const int eE = tid >> 5;          // example 0..7 (half-wave uniform)
    float acc[4];

    // layer 1: 288 -> 128, relu
    {
        float4 b = *(const float4*)&pb1[n4 * 4];
        acc[0] = b.x; acc[1] = b.y; acc[2] = b.z; acc[3] = b.w;
        for (int k = 0; k < 288; k++) {
            int i = (k & 31) * 9 + (k >> 5);
            float4 w = *(const float4*)&pw1[i * 128 + n4 * 4];
            float yv = ysT[k * 14 + eE];
            acc[0] = fmaf(yv, w.x, acc[0]); acc[1] = fmaf(yv, w.y, acc[1]);
            acc[2] = fmaf(yv, w.z, acc[2]); acc[3] = fmaf(yv, w.w, acc[3]);
        }
        #pragma unroll
        for (int j = 0; j < 4; j++)
            hAT[(n4 * 4 + j) * 14 + eE] = fmaxf(acc[j], 0.f);
    }
    __syncthreads();

    // layer 2: 128 -> 128, relu
    {
        float4 b = *(const float4*)&pb2[n4 * 4];
        acc[0] = b.x; acc[1] = b.y; acc[2] = b.z; acc[3] = b.w;
        for (int k = 0; k < 128; k++) {
            float4 w = *(const float4*)&pw2[k * 128 + n4 * 4];
            float hv = hAT[k * 14 + eE];
            acc[0] = fmaf(hv, w.x, acc[0]); acc[1] = fmaf(hv, w.y, acc[1]);
            acc[2] = fmaf(hv, w.z, acc[2]); acc[3] = fmaf(hv, w.w, acc[3]);
        }
        #pragma unroll
        for (int j = 0; j < 4; j++)
            hBT[(n4 * 4 + j) * 14 + eE] = fmaxf(acc[j], 0.f);
    }
    __syncthreads();

    // logits 128 -> 3: 24 (e,o) pairs x 2 K-partials of 64
    if (tid < 48) {
        int pr = tid & 1, eo = tid >> 1;
        int e = eo / 3, o = eo - e * 3;
        float s = pr ? 0.f : pb3[o];
        const int k0 = pr * 64;
        for (int k = k0; k < k0 + 64; k++) s = fmaf(hBT[k * 14 + e], pw3[k * 3 + o], s);
        lgp[tid] = s;
    }
    __syncthreads();
    if (tid < 8) {
        float l0 = lgp[(tid * 3 + 0) * 2] + lgp[(tid * 3 + 0) * 2 + 1];
        float l1 = lgp[(tid * 3 + 1) * 2] + lgp[(tid * 3 + 1) * 2 + 1];
        float l2 = lgp[(tid * 3 + 2) * 2] + lgp[(tid * 3 + 2) * 2 + 1];
        int a = 0; float best = l0;
        if (l1 > best) { best = l1; a = 1; }
        if (l2 > best) { best = l2; a = 2; }
        acts[tid] = a;
        out[4096 * 10 + img0 + tid] = (float)a;
    }
    __syncthreads();

    const int a = acts[eE];           // half-wave-uniform expert id

    // selection layer 1: 288 -> 128, single expert stream
    {
        const float* wb = ew1 + a * 36864;
        acc[0] = 0.f; acc[1] = 0.f; acc[2] = 0.f; acc[3] = 0.f;
        for (int k = 0; k < 288; k++) {
            int i = (k & 31) * 9 + (k >> 5);
            float4 w = *(const float4*)&wb[i * 128 + n4 * 4];
            float yv = ysT[k * 14 + eE];
            acc[0] = fmaf(yv, w.x, acc[0]); acc[1] = fmaf(yv, w.y, acc[1]);
            acc[2] = fmaf(yv, w.z, acc[2]); acc[3] = fmaf(yv, w.w, acc[3]);
        }
        float4 b = *(const float4*)&eb1[a * 128 + n4 * 4];
        hAT[(n4 * 4 + 0) * 14 + eE] = acc[0] + b.x;
        hAT[(n4 * 4 + 1) * 14 + eE] = acc[1] + b.y;
        hAT[(n4 * 4 + 2) * 14 + eE] = acc[2] + b.z;
        hAT[(n4 * 4 + 3) * 14 + eE] = acc[3] + b.w;
    }
    __syncthreads();

    // selection layer 2: 128 -> 128
    {
        const float* wb = ew2 + a * 16384;
        acc[0] = 0.f; acc[1] = 0.f; acc[2] = 0.f; acc[3] = 0.f;
        for (int k = 0; k < 128; k++) {
            float4 w = *(const float4*)&wb[k * 128 + n4 * 4];
            float hv = hAT[k * 14 + eE];
            acc[0] = fmaf(hv, w.x, acc[0]); acc[1] = fmaf(hv, w.y, acc[1]);
            acc[2] = fmaf(hv, w.z, acc[2]); acc[3] = fmaf(hv, w.w, acc[3]);
        }
        float4 b = *(const float4*)&eb2[a * 128 + n4 * 4];
        hBT[(n4 * 4 + 0) * 14 + eE] = acc[0] + b.x;
        hBT[(n4 * 4 + 1) * 14 + eE] = acc[1] + b.y;
        hBT[(n4 * 4 + 2) * 14 + eE] = acc[2] + b.z;
        hBT[(n4 * 4 + 3) * 14 + eE] = acc[3] + b.w;
    }
    __syncthreads();

    // selection layer 3: 128 -> 10: 80 (e,o) pairs x 2 K-partials of 64
    if (tid < 160) {
        int pr = (tid >= 80) ? 1 : 0;
        int idx = tid - pr * 80;
        int e = idx / 10, o = idx - e * 10;
        int aa = acts[e];
        const float* w3 = &ew3[aa * 1280];
        float s = pr ? 0.f : eb3[aa * 10 + o];
        const int k0 = pr * 64;
        for (int k = k0; k < k0 + 64; k++) s = fmaf(hBT[k * 14 + e], w3[k * 10 + o], s);
        sp[tid] = s;
    }
    __syncthreads();
    if (tid < 80) {
        int e = tid / 10, o = tid - e * 10;
        out[(img0 + e) * 10 + o] = sp[tid] + sp[tid + 80];
    }
}

// ---------------------------------------------------------------------------
extern "C" void kernel_launch(void* const* d_in, const int* in_sizes, int n_in,
                              void* d_out, int out_size, void* d_ws, size_t ws_size,
                              hipStream_t stream)
{
    const float* x   = (const float*)d_in[0];
    const float* cw1 = (const float*)d_in[1];
    const float* cb1 = (const float*)d_in[2];
    const float* cw2 = (const float*)d_in[3];
    const float* cb2 = (const float*)d_in[4];
    const float* cw3 = (const float*)d_in[5];
    const float* cb3 = (const float*)d_in[6];
    const float* bng = (const float*)d_in[7];
    const float* bnb = (const float*)d_in[8];
    const float* pw1 = (const float*)d_in[9];
    const float* pb1 = (const float*)d_in[10];
    const float* pw2 = (const float*)d_in[11];
    const float* pb2 = (const float*)d_in[12];
    const float* pw3 = (const float*)d_in[13];
    const float* pb3 = (const float*)d_in[14];
    const float* ew1 = (const float*)d_in[15];
    const float* eb1 = (const float*)d_in[16];
    const float* ew2 = (const float*)d_in[17];
    const float* eb2 = (const float*)d_in[18];
    const float* ew3 = (const float*)d_in[19];
    const float* eb3 = (const float*)d_in[20];

    float* out     = (float*)d_out;
    float* out3    = (float*)d_ws;                    // 4096*288
    float* gstats  = out3 + 4096 * 288;               // 64 (atomic S/SS)
    float* packed2 = gstats + 64;                     // 9216
    float* packed3 = packed2 + 9216;                  // 9216

    hipMemsetAsync(gstats, 0, 64 * sizeof(float), stream);
    repack_kernel<<<72, 256, 0, stream>>>(cw2, cw3, packed2, packed3);
    fused_conv_kernel<<<4096, 256, 0, stream>>>(x, cw1, cb1, packed2, cb2,
                                                packed3, cb3, out3, gstats);
    mlp_select_kernel<<<512, 256, 0, stream>>>(out3, gstats, bng, bnb,
                                               pw1, pb1, pw2, pb2, pw3, pb3,
                                               ew1, eb1, ew2, eb2, ew3, eb3, out);
}

// Round 15
// 418.279 us; speedup vs baseline: 1.3374x; 1.0048x over previous
//
#include <hip/hip_runtime.h>

// ---------------------------------------------------------------------------
// Kernel 0: repack conv2/conv3 weights into [ic*9+tap][oc] linear layout.
// ---------------------------------------------------------------------------
__global__ __launch_bounds__(256) void repack_kernel(
    const float* __restrict__ cw2, const float* __restrict__ cw3,
    float* __restrict__ packed2, float* __restrict__ packed3)
{
    int t = blockIdx.x * 256 + threadIdx.x;   // grid 72*256 = 18432 = 2*9216
    if (t < 9216) {
        int oc = t & 31, r = t >> 5;          // r = ic*9+tap in [0,288)
        packed2[t] = cw2[oc * 288 + r];
    } else {
        int t2 = t - 9216;
        int oc = t2 & 31, r = t2 >> 5;
        packed3[t2] = cw3[oc * 288 + r];
    }
}

// ---------------------------------------------------------------------------
// Kernel 1: fused conv stack (r12 structure: 38.4 KB LDS, 3 blocks/CU, ~81%
// VALUBusy) + fused BatchNorm partial-sum epilogue -> gstats[64] atomics.
// UNCHANGED from r14 (310 us, the measured winner).
// ---------------------------------------------------------------------------
__global__ __launch_bounds__(256)
void fused_conv_kernel(
    const float* __restrict__ x,
    const float* __restrict__ cw1, const float* __restrict__ cb1,
    const float* __restrict__ packed2, const float* __restrict__ cb2,
    const float* __restrict__ packed3, const float* __restrict__ cb3,
    float* __restrict__ out3, float* __restrict__ gstats)
{
    const int img = blockIdx.x;
    const int tid = threadIdx.x;

    __shared__ float A[1220];         // xs1(900)+w1s(288)+b1s(32) | wck2(1152)
    __shared__ float B[8320];         // xs2 (32 x 260) | scratch/xs3/wck3
    __shared__ float b2s[32], b3s[32];

    float* xs1  = A;                  // 900: 30x30 padded image
    float* w1s  = A + 900;            // 288
    float* b1s  = A + 1188;           // 32
    float* wck2 = A;                  // 1152: conv2 4-ic chunk (after conv1)
    float* xs2  = B;                  // 32 planes x 260
    float* sc   = B;                  // reduction scratch head
    float* xs3  = B + 1280;           // 2880: 32 x 90 -> [1280,4160)
    float* wck3 = B + 4160;           // 2304: conv3 8-ic chunk -> [4160,6464)
    float* sc2  = B + 5073;           // pool scratch -> [5102,8320)

    // --- zero xs1 pads + all of B ---
    for (int i = tid; i < 900;  i += 256) xs1[i] = 0.f;
    for (int i = tid; i < 8320; i += 256) B[i] = 0.f;
    __syncthreads();

    // --- stage input image + conv1 weights + biases ---
    for (int i = tid; i < 784; i += 256) {
        int yy = i / 28, xx = i % 28;
        xs1[(yy + 1) * 30 + xx + 1] = x[img * 784 + i];
    }
    for (int i = tid; i < 288; i += 256) {
        int oc = i & 31, tap = i >> 5;
        w1s[i] = cw1[oc * 9 + tap];
    }
    if (tid < 32) { b1s[tid] = cb1[tid]; b2s[tid] = cb2[tid]; b3s[tid] = cb3[tid]; }
    __syncthreads();

    // --- conv1 (1->32) + relu + pool -> xs2 (swizzled) ---
    {
        const int c1 = tid & 31;
        float w1r[9];
        #pragma unroll
        for (int t = 0; t < 9; t++) w1r[t] = w1s[t * 32 + c1];
        const float bias1 = b1s[c1];
        for (int o = tid; o < 32 * 196; o += 256) {
            int p = o >> 5;
            int py = p / 14, px = p % 14;
            int base = (2 * py) * 30 + 2 * px;
            float P[16];
            #pragma unroll
            for (int r = 0; r < 4; r++) {
                float2 u0 = *(const float2*)&xs1[base + r * 30];
                float2 u1 = *(const float2*)&xs1[base + r * 30 + 2];
                P[r * 4 + 0] = u0.x; P[r * 4 + 1] = u0.y;
                P[r * 4 + 2] = u1.x; P[r * 4 + 3] = u1.y;
            }
            float a00 = 0.f, a01 = 0.f, a10 = 0.f, a11 = 0.f;
            #pragma unroll
            for (int ky = 0; ky < 3; ky++)
                #pragma unroll
                for (int kx = 0; kx < 3; kx++) {
                    float w = w1r[ky * 3 + kx];
                    a00 = fmaf(P[ky * 4 + kx],           w, a00);
                    a01 = fmaf(P[ky * 4 + kx + 1],       w, a01);
                    a10 = fmaf(P[(ky + 1) * 4 + kx],     w, a10);
                    a11 = fmaf(P[(ky + 1) * 4 + kx + 1], w, a11);
                }
            float v = fmaxf(fmaxf(fmaxf(a00, a01), fmaxf(a10, a11)) + bias1, 0.f);
            int r = py + 1, col = px + 1;
            xs2[c1 * 260 + r * 16 + ((((col >> 2) + r) & 3) << 2) + (col & 3)] = v;
        }
    }

    // --- conv2: 4oc x 14 cols, K-split-2 over 8 chunks of 4 ic ---
    const int g  = tid >> 7;            // K-group 0..1 (2 waves each)
    const int u  = tid & 127;           // unit; active if u < 112
    const int cb = u & 7, R = u >> 3;   // oc-quad, prepool row 0..13
    const int oc0 = cb * 4;
    const bool act2 = (u < 112);

    float acc[4][14];
    #pragma unroll
    for (int a = 0; a < 4; a++)
        #pragma unroll
        for (int c = 0; c < 14; c++) acc[a][c] = 0.f;

    float pf[5];                        // 1152 = 4.5*256
    #pragma unroll
    for (int k = 0; k < 5; k++) {
        int idx = tid + k * 256;
        pf[k] = (idx < 1152) ? packed2[idx] : 0.f;
    }

    for (int ch = 0; ch < 8; ch++) {
        __syncthreads();                // conv1/xs2 writes + prior wck2 reads done
        #pragma unroll
        for (int k = 0; k < 5; k++) {
            int idx = tid + k * 256;
            if (idx < 1152) wck2[idx] = pf[k];
        }
        if (ch < 7) {
            #pragma unroll
            for (int k = 0; k < 5; k++) {
                int idx = tid + k * 256;
                pf[k] = (idx < 1152) ? packed2[(ch + 1) * 1152 + idx] : 0.f;
            }
        }
        __syncthreads();
        if (act2) {
            #pragma unroll
            for (int d = 0; d < 2; d++) {
                const int ld = g * 2 + d;            // local ic 0..3
                const int ic = ch * 4 + ld;
                const float* wd = &wck2[ld * 288 + oc0];
                const int pb = ic * 260;
                #pragma unroll
                for (int ky = 0; ky < 3; ky++) {
                    const int rp = R + ky;
                    const int rb = pb + rp * 16;
                    float row[16];
                    #pragma unroll
                    for (int q = 0; q < 4; q++) {
                        const float4 t = *(const float4*)&xs2[rb + (((q + rp) & 3) << 2)];
                        row[q * 4 + 0] = t.x; row[q * 4 + 1] = t.y;
                        row[q * 4 + 2] = t.z; row[q * 4 + 3] = t.w;
                    }
                    const float4 wa = *(const float4*)&wd[(ky * 3 + 0) * 32];
                    const float4 wb = *(const float4*)&wd[(ky * 3 + 1) * 32];
                    const float4 wc = *(const float4*)&wd[(ky * 3 + 2) * 32];
                    #pragma unroll
                    for (int c = 0; c < 14; c++) {
                        acc[0][c] = fmaf(row[c],     wa.x, acc[0][c]);
                        acc[1][c] = fmaf(row[c],     wa.y, acc[1][c]);
                        acc[2][c] = fmaf(row[c],     wa.z, acc[2][c]);
                        acc[3][c] = fmaf(row[c],     wa.w, acc[3][c]);
                        acc[0][c] = fmaf(row[c + 1], wb.x, acc[0][c]);
                        acc[1][c] = fmaf(row[c + 1], wb.y, acc[1][c]);
                        acc[2][c] = fmaf(row[c + 1], wb.z, acc[2][c]);
                        acc[3][c] = fmaf(row[c + 1], wb.w, acc[3][c]);
                        acc[0][c] = fmaf(row[c + 2], wc.x, acc[0][c]);
                        acc[1][c] = fmaf(row[c + 2], wc.y, acc[1][c]);
                        acc[2][c] = fmaf(row[c + 2], wc.z, acc[2][c]);
                        acc[3][c] = fmaf(row[c + 2], wc.w, acc[3][c]);
                    }
                }
            }
        }
    }

    // --- conv2 K-reduction (1 round, stride-57 scratch in B head, max 6382) ---
    __syncthreads();                     // all xs2 patch reads done
    if (g == 1 && act2) {
        #pragma unroll
        for (int a = 0; a < 4; a++)
            #pragma unroll
            for (int c = 0; c < 14; c++) sc[u * 57 + a * 14 + c] = acc[a][c];
    }
    __syncthreads();
    if (g == 0 && act2) {
        #pragma unroll
        for (int a = 0; a < 4; a++)
            #pragma unroll
            for (int c = 0; c < 14; c++) acc[a][c] += sc[u * 57 + a * 14 + c];
    }
    __syncthreads();                     // reduction scratch retires

    // --- zero xs3 + pool 14x14->7x7 (register hmax, odd/even R via sc2) ---
    for (int i = tid; i < 2880; i += 256) xs3[i] = 0.f;
    float hm[4][7];
    if (g == 0 && act2) {
        #pragma unroll
        for (int a = 0; a < 4; a++)
            #pragma unroll
            for (int c = 0; c < 7; c++)
                hm[a][c] = fmaxf(acc[a][2 * c], acc[a][2 * c + 1]);
        if (R & 1) {                     // sc2 idx max 111*29+27=3246 -> abs 8319
            #pragma unroll
            for (int a = 0; a < 4; a++)
                #pragma unroll
                for (int c = 0; c < 7; c++) sc2[u * 29 + a * 7 + c] = hm[a][c];
        }
    }
    __syncthreads();
    if (g == 0 && act2 && !(R & 1)) {
        const int py = R >> 1;           // 0..6
        #pragma unroll
        for (int a = 0; a < 4; a++)
            #pragma unroll
            for (int c = 0; c < 7; c++) {
                float v = fmaxf(hm[a][c], sc2[(u + 8) * 29 + a * 7 + c]);
                v = fmaxf(v + b2s[oc0 + a], 0.f);
                xs3[(oc0 + a) * 90 + (py + 1) * 10 + (c + 1)] = v;
            }
    }

    // --- conv3 (32->32, 7x7) + relu + pool(7->3 floor), K-split-2 ---
    const int u3 = tid & 127;
    const bool act3 = (u3 < 72);
    const int cq3 = u3 & 7, pos = u3 >> 3;   // oc-quad, pooled pos 0..8
    const int oc30 = cq3 * 4;
    const int py3 = pos / 3, px3 = pos % 3;
    const int base3 = (2 * py3) * 10 + 2 * px3;

    float a3[4][4];
    #pragma unroll
    for (int a = 0; a < 4; a++)
        #pragma unroll
        for (int q = 0; q < 4; q++) a3[a][q] = 0.f;

    float pg[9];                        // 2304 = 9*256
    #pragma unroll
    for (int k = 0; k < 9; k++) pg[k] = packed3[tid + k * 256];

    for (int ch = 0; ch < 4; ch++) {
        __syncthreads();                 // pool/xs3 writes + prior wck3 reads done
        #pragma unroll
        for (int k = 0; k < 9; k++) wck3[tid + k * 256] = pg[k];
        if (ch < 3) {
            #pragma unroll
            for (int k = 0; k < 9; k++) pg[k] = packed3[(ch + 1) * 2304 + tid + k * 256];
        }
        __syncthreads();
        if (act3) {
            #pragma unroll 2
            for (int d = 0; d < 4; d++) {
                const int ld = g * 4 + d;
                const int ic = ch * 8 + ld;
                const float* xp = &xs3[ic * 90 + base3];
                float P[16];
                #pragma unroll
                for (int r = 0; r < 4; r++) {
                    float2 u0 = *(const float2*)&xp[r * 10];
                    float2 u1 = *(const float2*)&xp[r * 10 + 2];
                    P[r * 4 + 0] = u0.x; P[r * 4 + 1] = u0.y;
                    P[r * 4 + 2] = u1.x; P[r * 4 + 3] = u1.y;
                }
                const float* wd = &wck3[ld * 288 + oc30];
                #pragma unroll
                for (int tap = 0; tap < 9; tap++) {
                    const int ky = tap / 3, kx = tap % 3;
                    const float4 wv = *(const float4*)&wd[tap * 32];
                    const float x00 = P[ky * 4 + kx];
                    const float x01 = P[ky * 4 + kx + 1];
                    const float x10 = P[(ky + 1) * 4 + kx];
                    const float x11 = P[(ky + 1) * 4 + kx + 1];
                    a3[0][0] = fmaf(x00, wv.x, a3[0][0]); a3[0][1] = fmaf(x01, wv.x, a3[0][1]);
                    a3[0][2] = fmaf(x10, wv.x, a3[0][2]); a3[0][3] = fmaf(x11, wv.x, a3[0][3]);
                    a3[1][0] = fmaf(x00, wv.y, a3[1][0]); a3[1][1] = fmaf(x01, wv.y, a3[1][1]);
                    a3[1][2] = fmaf(x10, wv.y, a3[1][2]); a3[1][3] = fmaf(x11, wv.y, a3[1][3]);
                    a3[2][0] = fmaf(x00, wv.z, a3[2][0]); a3[2][1] = fmaf(x01, wv.z, a3[2][1]);
                    a3[2][2] = fmaf(x10, wv.z, a3[2][2]); a3[2][3] = fmaf(x11, wv.z, a3[2][3]);
                    a3[3][0] = fmaf(x00, wv.w, a3[3][0]); a3[3][1] = fmaf(x01, wv.w, a3[3][1]);
                    a3[3][2] = fmaf(x10, wv.w, a3[3][2]); a3[3][3] = fmaf(x11, wv.w, a3[3][3]);
                }
            }
        }
    }

    // --- conv3 K-reduction (1 round, stride-17 scratch in head, max 1222) ---
    __syncthreads();
    if (g == 1 && act3) {
        #pragma unroll
        for (int a = 0; a < 4; a++)
            #pragma unroll
            for (int q = 0; q < 4; q++) sc[u3 * 17 + a * 4 + q] = a3[a][q];
    }
    __syncthreads();
    float rres[4];
    const bool writer = (g == 0 && act3);
    if (writer) {
        #pragma unroll
        for (int a = 0; a < 4; a++)
            #pragma unroll
            for (int q = 0; q < 4; q++) a3[a][q] += sc[u3 * 17 + a * 4 + q];
        float4 res;
        #pragma unroll
        for (int a = 0; a < 4; a++) {
            float v = fmaxf(fmaxf(a3[a][0], a3[a][1]), fmaxf(a3[a][2], a3[a][3]));
            rres[a] = fmaxf(v + b3s[oc30 + a], 0.f);
        }
        res.x = rres[0]; res.y = rres[1]; res.z = rres[2]; res.w = rres[3];
        *(float4*)&out3[img * 288 + pos * 32 + oc30] = res;
    }

    // --- fused BN partial sums: single-writer LDS grid then 64 atomics ---
    __syncthreads();                     // sc reads done -> B reusable
    for (int i = tid; i < 576; i += 256) B[i] = 0.f;
    __syncthreads();
    if (writer) {
        #pragma unroll
        for (int a = 0; a < 4; a++) {
            B[pos * 64 + oc30 + a]      = rres[a];
            B[pos * 64 + 32 + oc30 + a] = rres[a] * rres[a];
        }
    }
    __syncthreads();
    if (tid < 64) {
        int c = tid & 31, part = tid >> 5;   // part 0 = S, 1 = SS
        float s = 0.f;
        #pragma unroll
        for (int p = 0; p < 9; p++) s += B[p * 64 + part * 32 + c];
        atomicAdd(&gstats[part * 32 + c], s);
    }
}

// ---------------------------------------------------------------------------
// Kernel 3: BN-finalize (folded) + BN-apply + MLP + argmax + 3 selection
// layers. 512 blocks x 256 threads x 8 examples.
// NEW: layer1/layer2 weights staged through LDS in K=32 tiles (wst, 16 KB):
// per-block global requests for these layers drop 8x (each weight word loaded
// once per block instead of once per eE half-wave) and become dense/coalesced
// -> attacks the measured load-latency bound (~104 us tail vs ~25 us L2-BW
// floor). FMA order unchanged -> bit-exact vs r14. sel1/sel2 keep direct
// expert streams (mixed experts per block).
// ---------------------------------------------------------------------------
__global__ __launch_bounds__(256) void mlp_select_kernel(
    const float* __restrict__ out3, const float* __restrict__ gstats,
    const float* __restrict__ bng, const float* __restrict__ bnb,
    const float* __restrict__ pw1, const float* __restrict__ pb1,
    const float* __restrict__ pw2, const float* __restrict__ pb2,
    const float* __restrict__ pw3, const float* __restrict__ pb3,
    const float* __restrict__ ew1, const float* __restrict__ eb1,
    const float* __restrict__ ew2, const float* __restrict__ eb2,
    const float* __restrict__ ew3, const float* __restrict__ eb3,
    float* __restrict__ out)
{
    const int tid = threadIdx.x;
    const int img0 = blockIdx.x * 8;

    __shared__ float ysT[288 * 14];   // [j][e], stride 14
    __shared__ float hAT[128 * 14];
    __shared__ float hBT[128 * 14];
    __shared__ float wst[32 * 128];   // staged weight tile (16 KB)
    __shared__ float lgp[48];
    __shared__ float sp[160];
    __shared__ int   acts[8];
    __shared__ float sa[32], sb[32];

    // BN finalize from global atomic sums (redundant per block; ~free)
    if (tid < 32) {
        float S = gstats[tid], SS = gstats[32 + tid];
        const float inv_n = 1.f / (4096.f * 9.f);
        float mean = S * inv_n;
        float var = SS * inv_n - mean * mean;
        float a = bng[tid] * rsqrtf(var + 1e-5f);
        sa[tid] = a;
        sb[tid] = bnb[tid] - a * mean;
    }
    __syncthreads();

    // stage + BN: 8*72 = 576 float4 reads, scatter-transpose into ysT
    for (int it = 0; it < 3; it++) {
        int i4 = it * 256 + tid;
        if (i4 < 576) {
            int e = i4 / 72, jq = i4 - e * 72;
            float4 v = *(const float4*)&out3[(img0 + e) * 288 + jq * 4];
            int j = jq * 4;
            ysT[(j + 0) * 14 + e] = fmaf(sa[(j + 0) & 31], v.x, sb[(j + 0) & 31]);
            ysT[(j + 1) * 14 + e] = fmaf(sa[(j + 1) & 31], v.y, sb[(j + 1) & 31]);
            ysT[(j + 2) * 14 + e] = fmaf(sa[(j + 2) & 31], v.z, sb[(j + 2) & 31]);
            ysT[(j + 3) * 14 + e] = fmaf(sa[(j + 3) & 31], v.w, sb[(j + 3) & 31]);
        }
    }

    const int n4 = tid & 31;          // neuron quad: n = n4*4 .. n4*4+3
    const int eE = tid >> 5;          // example 0..7 (half-wave uniform)
    const int srow = tid >> 5;        // staging row group (0..7)
    const int sc4 = tid & 31;         // staging float4 column
    float acc[4];

    // layer 1: 288 -> 128, relu — K tiled by 32, weights staged in LDS
    {
        float4 b = *(const float4*)&pb1[n4 * 4];
        acc[0] = b.x; acc[1] = b.y; acc[2] = b.z; acc[3] = b.w;
        for (int t = 0; t < 9; t++) {
            __syncthreads();          // first iter also covers ysT staging
            #pragma unroll
            for (int s = 0; s < 4; s++) {
                int row = s * 8 + srow;
                int k = t * 32 + row;
                int i = (k & 31) * 9 + (k >> 5);
                *(float4*)&wst[row * 128 + sc4 * 4] =
                    *(const float4*)&pw1[i * 128 + sc4 * 4];
            }
            __syncthreads();
            for (int j = 0; j < 32; j++) {
                float4 w = *(const float4*)&wst[j * 128 + n4 * 4];
                float yv = ysT[(t * 32 + j) * 14 + eE];
                acc[0] = fmaf(yv, w.x, acc[0]); acc[1] = fmaf(yv, w.y, acc[1]);
                acc[2] = fmaf(yv, w.z, acc[2]); acc[3] = fmaf(yv, w.w, acc[3]);
            }
        }
        #pragma unroll
        for (int j = 0; j < 4; j++)
            hAT[(n4 * 4 + j) * 14 + eE] = fmaxf(acc[j], 0.f);
    }

    // layer 2: 128 -> 128, relu — staged tiles
    {
        float4 b = *(const float4*)&pb2[n4 * 4];
        acc[0] = b.x; acc[1] = b.y; acc[2] = b.z; acc[3] = b.w;
        for (int t = 0; t < 4; t++) {
            __syncthreads();          // hAT writes + prior wst reads done
            #pragma unroll
            for (int s = 0; s < 4; s++) {
                int row = s * 8 + srow;
                int k = t * 32 + row;
                *(float4*)&wst[row * 128 + sc4 * 4] =
                    *(const float4*)&pw2[k * 128 + sc4 * 4];
            }
            __syncthreads();
            for (int j = 0; j < 32; j++) {
                float4 w = *(const float4*)&wst[j * 128 + n4 * 4];
                float hv = hAT[(t * 32 + j) * 14 + eE];
                acc[0] = fmaf(hv, w.x, acc[0]); acc[1] = fmaf(hv, w.y, acc[1]);
                acc[2] = fmaf(hv, w.z, acc[2]); acc[3] = fmaf(hv, w.w, acc[3]);
            }
        }
        #pragma unroll
        for (int j = 0; j < 4; j++)
            hBT[(n4 * 4 + j) * 14 + eE] = fmaxf(acc[j], 0.f);
    }
    __syncthreads();

    // logits 128 -> 3: 24 (e,o) pairs x 2 K-partials of 64
    if (tid < 48) {
        int pr = tid & 1, eo = tid >> 1;
        int e = eo / 3, o = eo - e * 3;
        float s = pr ? 0.f : pb3[o];
        const int k0 = pr * 64;
        for (int k = k0; k < k0 + 64; k++) s = fmaf(hBT[k * 14 + e], pw3[k * 3 + o], s);
        lgp[tid] = s;
    }
    __syncthreads();
    if (tid < 8) {
        float l0 = lgp[(tid * 3 + 0) * 2] + lgp[(tid * 3 + 0) * 2 + 1];
        float l1 = lgp[(tid * 3 + 1) * 2] + lgp[(tid * 3 + 1) * 2 + 1];
        float l2 = lgp[(tid * 3 + 2) * 2] + lgp[(tid * 3 + 2) * 2 + 1];
        int a = 0; float best = l0;
        if (l1 > best) { best = l1; a = 1; }
        if (l2 > best) { best = l2; a = 2; }
        acts[tid] = a;
        out[4096 * 10 + img0 + tid] = (float)a;
    }
    __syncthreads();

    const int a = acts[eE];           // half-wave-uniform expert id

    // selection layer 1: 288 -> 128, single expert stream
    {
        const float* wb = ew1 + a * 36864;
        acc[0] = 0.f; acc[1] = 0.f; acc[2] = 0.f; acc[3] = 0.f;
        for (int k = 0; k < 288; k++) {
            int i = (k & 31) * 9 + (k >> 5);
            float4 w = *(const float4*)&wb[i * 128 + n4 * 4];
            float yv = ysT[k * 14 + eE];
            acc[0] = fmaf(yv, w.x, acc[0]); acc[1] = fmaf(yv, w.y, acc[1]);
            acc[2] = fmaf(yv, w.z, acc[2]); acc[3] = fmaf(yv, w.w, acc[3]);
        }
        float4 b = *(const float4*)&eb1[a * 128 + n4 * 4];
        hAT[(n4 * 4 + 0) * 14 + eE] = acc[0] + b.x;
        hAT[(n4 * 4 + 1) * 14 + eE] = acc[1] + b.y;
        hAT[(n4 * 4 + 2) * 14 + eE] = acc[2] + b.z;
        hAT[(n4 * 4 + 3) * 14 + eE] = acc[3] + b.w;
    }
    __syncthreads();

    // selection layer 2: 128 -> 128
    {
        const float* wb = ew2 + a * 16384;
        acc[0] = 0.f; acc[1] = 0.f; acc[2] = 0.f; acc[3] = 0.f;
        for (int k = 0; k < 128; k++) {
            float4 w = *(const float4*)&wb[k * 128 + n4 * 4];
            float hv = hAT[k * 14 + eE];
            acc[0] = fmaf(hv, w.x, acc[0]); acc[1] = fmaf(hv, w.y, acc[1]);
            acc[2] = fmaf(hv, w.z, acc[2]); acc[3] = fmaf(hv, w.w, acc[3]);
        }
        float4 b = *(const float4*)&eb2[a * 128 + n4 * 4];
        hBT[(n4 * 4 + 0) * 14 + eE] = acc[0] + b.x;
        hBT[(n4 * 4 + 1) * 14 + eE] = acc[1] + b.y;
        hBT[(n4 * 4 + 2) * 14 + eE] = acc[2] + b.z;
        hBT[(n4 * 4 + 3) * 14 + eE] = acc[3] + b.w;
    }
    __syncthreads();

    // selection layer 3: 128 -> 10: 80 (e,o) pairs x 2 K-partials of 64
    if (tid < 160) {
        int pr = (tid >= 80) ? 1 : 0;
        int idx = tid - pr * 80;
        int e = idx / 10, o = idx - e * 10;
        int aa = acts[e];
        const float* w3 = &ew3[aa * 1280];
        float s = pr ? 0.f : eb3[aa * 10 + o];
        const int k0 = pr * 64;
        for (int k = k0; k < k0 + 64; k++) s = fmaf(hBT[k * 14 + e], w3[k * 10 + o], s);
        sp[tid] = s;
    }
    __syncthreads();
    if (tid < 80) {
        int e = tid / 10, o = tid - e * 10;
        out[(img0 + e) * 10 + o] = sp[tid] + sp[tid + 80];
    }
}

// ---------------------------------------------------------------------------
extern "C" void kernel_launch(void* const* d_in, const int* in_sizes, int n_in,
                              void* d_out, int out_size, void* d_ws, size_t ws_size,
                              hipStream_t stream)
{
    const float* x   = (const float*)d_in[0];
    const float* cw1 = (const float*)d_in[1];
    const float* cb1 = (const float*)d_in[2];
    const float* cw2 = (const float*)d_in[3];
    const float* cb2 = (const float*)d_in[4];
    const float* cw3 = (const float*)d_in[5];
    const float* cb3 = (const float*)d_in[6];
    const float* bng = (const float*)d_in[7];
    const float* bnb = (const float*)d_in[8];
    const float* pw1 = (const float*)d_in[9];
    const float* pb1 = (const float*)d_in[10];
    const float* pw2 = (const float*)d_in[11];
    const float* pb2 = (const float*)d_in[12];
    const float* pw3 = (const float*)d_in[13];
    const float* pb3 = (const float*)d_in[14];
    const float* ew1 = (const float*)d_in[15];
    const float* eb1 = (const float*)d_in[16];
    const float* ew2 = (const float*)d_in[17];
    const float* eb2 = (const float*)d_in[18];
    const float* ew3 = (const float*)d_in[19];
    const float* eb3 = (const float*)d_in[20];

    float* out     = (float*)d_out;
    float* out3    = (float*)d_ws;                    // 4096*288
    float* gstats  = out3 + 4096 * 288;               // 64 (atomic S/SS)
    float* packed2 = gstats + 64;                     // 9216
    float* packed3 = packed2 + 9216;                  // 9216

    hipMemsetAsync(gstats, 0, 64 * sizeof(float), stream);
    repack_kernel<<<72, 256, 0, stream>>>(cw2, cw3, packed2, packed3);
    fused_conv_kernel<<<4096, 256, 0, stream>>>(x, cw1, cb1, packed2, cb2,
                                                packed3, cb3, out3, gstats);
    mlp_select_kernel<<<512, 256, 0, stream>>>(out3, gstats, bng, bnb,
                                               pw1, pb1, pw2, pb2, pw3, pb3,
                                               ew1, eb1, ew2, eb2, ew3, eb3, out);
}